// Round 4
// baseline (1952.818 us; speedup 1.0000x reference)
//
#include <hip/hip_runtime.h>
#include <hip/hip_bf16.h>
#include <stdint.h>

#define B_ 8
#define T_ 2048
#define C_ 384
#define H_ 6
#define D_ 64
#define M_ (B_*T_)   // 16384

typedef unsigned short u16;

__device__ __forceinline__ float b2f(u16 v) {
  union { unsigned u; float f; } x; x.u = ((unsigned)v) << 16; return x.f;
}
__device__ __forceinline__ u16 f2b(float f) {
  union { float f; unsigned u; } x; x.f = f;
  unsigned r = x.u + 0x7fffu + ((x.u >> 16) & 1u);  // round-nearest-even
  return (u16)(r >> 16);
}

// ---------------------------------------------------------------------------
// Kernel 1: fused QKV projection (fp32 inputs).  q[m,n] = sum_k x[m,k]*W[n,k]
// grid = (M/64, 384/64, 3); z picks Wq/Wk/Wv. Output scattered to [B][H][T][D]
// as bf16.
// ---------------------------------------------------------------------------
__global__ __launch_bounds__(256) void qkv_gemm(
    const float* __restrict__ Xg,
    const float* __restrict__ Wqg, const float* __restrict__ Wkg, const float* __restrict__ Wvg,
    u16* __restrict__ Qo, u16* __restrict__ Ko, u16* __restrict__ Vo)
{
  const int z = blockIdx.z;
  const float* Wg = (z == 0) ? Wqg : (z == 1 ? Wkg : Wvg);
  u16* Og = (z == 0) ? Qo : (z == 1 ? Ko : Vo);
  const int m0 = blockIdx.x * 64;
  const int n0 = blockIdx.y * 64;

  __shared__ float As[32][68];  // [k][m]
  __shared__ float Bs[32][68];  // [k][n]

  const int tid = threadIdx.x;
  const int lr = tid >> 2;          // 0..63 staging row
  const int lc = (tid & 3) * 8;     // 0,8,16,24 staging col
  const int tr = tid >> 4;          // 0..15 -> rows tr*4..+3
  const int tc = tid & 15;          // 0..15 -> cols tc*4..+3

  float acc[4][4] = {};

  for (int k0 = 0; k0 < 384; k0 += 32) {
    float4 xa = *reinterpret_cast<const float4*>(Xg + (size_t)(m0 + lr) * C_ + k0 + lc);
    float4 xb = *reinterpret_cast<const float4*>(Xg + (size_t)(m0 + lr) * C_ + k0 + lc + 4);
    float4 wa = *reinterpret_cast<const float4*>(Wg + (size_t)(n0 + lr) * C_ + k0 + lc);
    float4 wb = *reinterpret_cast<const float4*>(Wg + (size_t)(n0 + lr) * C_ + k0 + lc + 4);
    __syncthreads();
    As[lc + 0][lr] = xa.x; As[lc + 1][lr] = xa.y; As[lc + 2][lr] = xa.z; As[lc + 3][lr] = xa.w;
    As[lc + 4][lr] = xb.x; As[lc + 5][lr] = xb.y; As[lc + 6][lr] = xb.z; As[lc + 7][lr] = xb.w;
    Bs[lc + 0][lr] = wa.x; Bs[lc + 1][lr] = wa.y; Bs[lc + 2][lr] = wa.z; Bs[lc + 3][lr] = wa.w;
    Bs[lc + 4][lr] = wb.x; Bs[lc + 5][lr] = wb.y; Bs[lc + 6][lr] = wb.z; Bs[lc + 7][lr] = wb.w;
    __syncthreads();
#pragma unroll
    for (int kk = 0; kk < 32; kk++) {
      float4 a = *reinterpret_cast<const float4*>(&As[kk][tr * 4]);
      float4 b = *reinterpret_cast<const float4*>(&Bs[kk][tc * 4]);
      acc[0][0] += a.x * b.x; acc[0][1] += a.x * b.y; acc[0][2] += a.x * b.z; acc[0][3] += a.x * b.w;
      acc[1][0] += a.y * b.x; acc[1][1] += a.y * b.y; acc[1][2] += a.y * b.z; acc[1][3] += a.y * b.w;
      acc[2][0] += a.z * b.x; acc[2][1] += a.z * b.y; acc[2][2] += a.z * b.z; acc[2][3] += a.z * b.w;
      acc[3][0] += a.w * b.x; acc[3][1] += a.w * b.y; acc[3][2] += a.w * b.z; acc[3][3] += a.w * b.w;
    }
  }

  // scatter to [B][H][T][D]; block column n0 = one head (n0 multiple of 64)
  const int hh = n0 >> 6;
#pragma unroll
  for (int i = 0; i < 4; i++) {
    int m = m0 + tr * 4 + i;
    int b = m >> 11, t = m & (T_ - 1);
    size_t idx = (((size_t)(b * H_ + hh)) * T_ + t) * D_ + tc * 4;
    ushort4 pk;
    pk.x = f2b(acc[i][0]); pk.y = f2b(acc[i][1]); pk.z = f2b(acc[i][2]); pk.w = f2b(acc[i][3]);
    *reinterpret_cast<ushort4*>(Og + idx) = pk;
  }
}

// ---------------------------------------------------------------------------
// Kernel 2: RoPE + RMSNorm in-place on Q and K ([B][H][T][D] bf16 rows).
// One wave per row; 4 rows per 256-thread block. Rows: 2*B*H*T (Q then K).
// cos/sin fp32.
// ---------------------------------------------------------------------------
__global__ __launch_bounds__(256) void rope_rms(
    u16* __restrict__ Q, u16* __restrict__ K,
    const float* __restrict__ cosb, const float* __restrict__ sinb)
{
  const int R = B_ * H_ * T_;
  int row = blockIdx.x * 4 + (threadIdx.x >> 6);
  int lane = threadIdx.x & 63;
  u16* base = (row < R) ? Q : K;
  int r = (row < R) ? row : row - R;
  int t = r & (T_ - 1);          // r = (b*H+h)*T + t
  u16* p = base + (size_t)r * D_;

  float v = b2f(p[lane]);
  int ci = t * 32 + (lane & 31);
  float c = cosb[ci], s = sinb[ci];
  float partner = __shfl_xor(v, 32, 64);
  // y1 = x1*c + x2*s ; y2 = -x1*s + x2*c
  float y = (lane < 32) ? (v * c + partner * s) : (v * c - partner * s);

  float ss = y * y;
#pragma unroll
  for (int off = 1; off < 64; off <<= 1) ss += __shfl_xor(ss, off, 64);
  float scale = rsqrtf(ss * (1.0f / 64.0f) + 1e-5f);
  p[lane] = f2b(y * scale);
}

// ---------------------------------------------------------------------------
// Kernel 3: flash attention per (b,h). BQ=32 q-rows per block, key tiles of 64.
// Thread (rr=tid>>3, cc=tid&7): computes S[rr][cc*8+jj] and O[rr][cc*8+dd].
// XOR-swizzled fp32 LDS tiles (stride 64) to avoid bank conflicts.
// ---------------------------------------------------------------------------
__device__ __forceinline__ int swzKV(int row, int col) {
  int g = (col >> 2) ^ ((row >> 3) & 7);
  return (row << 6) + (g << 2) + (col & 3);
}
__device__ __forceinline__ int swzQ(int row, int col) {
  int g = (col >> 2) ^ (row & 7);
  return (row << 6) + (g << 2) + (col & 3);
}

__global__ __launch_bounds__(256) void attn(
    const u16* __restrict__ Qg, const u16* __restrict__ Kg,
    const u16* __restrict__ Vg, u16* __restrict__ Yg)
{
  __shared__ float Qs[32 * 64];
  __shared__ float Ks[64 * 64];
  __shared__ float Vs[64 * 64];
  __shared__ float Ps[32 * 68];

  const int bh = blockIdx.y;
  const int q0 = blockIdx.x * 32;
  const size_t base = (size_t)bh * T_ * D_;
  const u16* Qb = Qg + base + (size_t)q0 * D_;
  const u16* Kb = Kg + base;
  const u16* Vb = Vg + base;

  const int tid = threadIdx.x;
  // Q staging: 32x64, 8 elems/thread; fold 1/sqrt(D)=0.125 into Q
  {
    int r = tid >> 3, c = (tid & 7) * 8;
    uint4 xa = *reinterpret_cast<const uint4*>(Qb + r * D_ + c);
    const u16* xs = reinterpret_cast<const u16*>(&xa);
#pragma unroll
    for (int i = 0; i < 8; i++) Qs[swzQ(r, c + i)] = b2f(xs[i]) * 0.125f;
  }

  const int rr = tid >> 3;        // 0..31 q-row
  const int cc = tid & 7;         // 0..7
  const int sr = tid >> 2;        // 0..63 staging row
  const int sc = (tid & 3) * 16;  // staging col

  float m = -1e30f, l = 0.0f;
  float o[8] = {0, 0, 0, 0, 0, 0, 0, 0};

  for (int kt = 0; kt < T_; kt += 64) {
    uint4 ka = *reinterpret_cast<const uint4*>(Kb + (size_t)(kt + sr) * D_ + sc);
    uint4 kb = *reinterpret_cast<const uint4*>(Kb + (size_t)(kt + sr) * D_ + sc + 8);
    uint4 va = *reinterpret_cast<const uint4*>(Vb + (size_t)(kt + sr) * D_ + sc);
    uint4 vb = *reinterpret_cast<const uint4*>(Vb + (size_t)(kt + sr) * D_ + sc + 8);
    __syncthreads();
    {
      const u16* ks = reinterpret_cast<const u16*>(&ka);
      const u16* ks2 = reinterpret_cast<const u16*>(&kb);
      const u16* vs = reinterpret_cast<const u16*>(&va);
      const u16* vs2 = reinterpret_cast<const u16*>(&vb);
#pragma unroll
      for (int i = 0; i < 8; i++) {
        Ks[swzKV(sr, sc + i)] = b2f(ks[i]);
        Ks[swzKV(sr, sc + 8 + i)] = b2f(ks2[i]);
        Vs[swzKV(sr, sc + i)] = b2f(vs[i]);
        Vs[swzKV(sr, sc + 8 + i)] = b2f(vs2[i]);
      }
    }
    __syncthreads();

    // S = Qs @ Ks^T  (8 keys per thread)
    float s[8];
#pragma unroll
    for (int jj = 0; jj < 8; jj++) s[jj] = 0.0f;
#pragma unroll
    for (int d = 0; d < 64; d += 4) {
      float4 q4 = *reinterpret_cast<const float4*>(&Qs[swzQ(rr, d)]);
#pragma unroll
      for (int jj = 0; jj < 8; jj++) {
        float4 k4 = *reinterpret_cast<const float4*>(&Ks[swzKV(cc * 8 + jj, d)]);
        s[jj] += q4.x * k4.x + q4.y * k4.y + q4.z * k4.z + q4.w * k4.w;
      }
    }

    // online softmax (row = 8 contiguous lanes)
    float mx = s[0];
#pragma unroll
    for (int jj = 1; jj < 8; jj++) mx = fmaxf(mx, s[jj]);
    mx = fmaxf(mx, __shfl_xor(mx, 1));
    mx = fmaxf(mx, __shfl_xor(mx, 2));
    mx = fmaxf(mx, __shfl_xor(mx, 4));
    float m_new = fmaxf(m, mx);
    float alpha = __expf(m - m_new);
    float ps = 0.0f;
#pragma unroll
    for (int jj = 0; jj < 8; jj++) {
      float pv = __expf(s[jj] - m_new);
      ps += pv;
      Ps[rr * 68 + cc * 8 + jj] = pv;
    }
    ps += __shfl_xor(ps, 1);
    ps += __shfl_xor(ps, 2);
    ps += __shfl_xor(ps, 4);
    l = l * alpha + ps;
    m = m_new;
#pragma unroll
    for (int dd = 0; dd < 8; dd++) o[dd] *= alpha;
    __syncthreads();

    // O += P @ V
#pragma unroll 8
    for (int j = 0; j < 64; j++) {
      float pj = Ps[rr * 68 + j];
      float4 v0 = *reinterpret_cast<const float4*>(&Vs[swzKV(j, cc * 8)]);
      float4 v1 = *reinterpret_cast<const float4*>(&Vs[swzKV(j, cc * 8 + 4)]);
      o[0] += pj * v0.x; o[1] += pj * v0.y; o[2] += pj * v0.z; o[3] += pj * v0.w;
      o[4] += pj * v1.x; o[5] += pj * v1.y; o[6] += pj * v1.z; o[7] += pj * v1.w;
    }
  }

  // epilogue: Y[b][t][h][d]
  float inv = 1.0f / l;
  int b = bh / H_, h = bh % H_;
  int t = q0 + rr;
  size_t yi = ((size_t)b * T_ + t) * C_ + h * D_ + cc * 8;
  ushort4 w0, w1;
  w0.x = f2b(o[0] * inv); w0.y = f2b(o[1] * inv); w0.z = f2b(o[2] * inv); w0.w = f2b(o[3] * inv);
  w1.x = f2b(o[4] * inv); w1.y = f2b(o[5] * inv); w1.z = f2b(o[6] * inv); w1.w = f2b(o[7] * inv);
  *reinterpret_cast<ushort4*>(Yg + yi) = w0;
  *reinterpret_cast<ushort4*>(Yg + yi + 4) = w1;
}

// ---------------------------------------------------------------------------
// Kernel 4: out = Y @ Wo^T.  Y bf16 (ws), Wo fp32 (input), out fp32 (d_out).
// ---------------------------------------------------------------------------
__global__ __launch_bounds__(256) void out_gemm(
    const u16* __restrict__ Xg, const float* __restrict__ Wg, float* __restrict__ Og)
{
  const int m0 = blockIdx.x * 64;
  const int n0 = blockIdx.y * 64;

  __shared__ float As[32][68];
  __shared__ float Bs[32][68];

  const int tid = threadIdx.x;
  const int lr = tid >> 2;
  const int lc = (tid & 3) * 8;
  const int tr = tid >> 4;
  const int tc = tid & 15;

  float acc[4][4] = {};

  for (int k0 = 0; k0 < 384; k0 += 32) {
    uint4 xa = *reinterpret_cast<const uint4*>(Xg + (size_t)(m0 + lr) * C_ + k0 + lc);
    float4 wa = *reinterpret_cast<const float4*>(Wg + (size_t)(n0 + lr) * C_ + k0 + lc);
    float4 wb = *reinterpret_cast<const float4*>(Wg + (size_t)(n0 + lr) * C_ + k0 + lc + 4);
    __syncthreads();
    const u16* xs = reinterpret_cast<const u16*>(&xa);
#pragma unroll
    for (int i = 0; i < 8; i++) As[lc + i][lr] = b2f(xs[i]);
    Bs[lc + 0][lr] = wa.x; Bs[lc + 1][lr] = wa.y; Bs[lc + 2][lr] = wa.z; Bs[lc + 3][lr] = wa.w;
    Bs[lc + 4][lr] = wb.x; Bs[lc + 5][lr] = wb.y; Bs[lc + 6][lr] = wb.z; Bs[lc + 7][lr] = wb.w;
    __syncthreads();
#pragma unroll
    for (int kk = 0; kk < 32; kk++) {
      float4 a = *reinterpret_cast<const float4*>(&As[kk][tr * 4]);
      float4 b = *reinterpret_cast<const float4*>(&Bs[kk][tc * 4]);
      acc[0][0] += a.x * b.x; acc[0][1] += a.x * b.y; acc[0][2] += a.x * b.z; acc[0][3] += a.x * b.w;
      acc[1][0] += a.y * b.x; acc[1][1] += a.y * b.y; acc[1][2] += a.y * b.z; acc[1][3] += a.y * b.w;
      acc[2][0] += a.z * b.x; acc[2][1] += a.z * b.y; acc[2][2] += a.z * b.z; acc[2][3] += a.z * b.w;
      acc[3][0] += a.w * b.x; acc[3][1] += a.w * b.y; acc[3][2] += a.w * b.z; acc[3][3] += a.w * b.w;
    }
  }

#pragma unroll
  for (int i = 0; i < 4; i++) {
    int mrow = m0 + tr * 4 + i;
    size_t idx = (size_t)mrow * C_ + n0 + tc * 4;
    float4 pk;
    pk.x = acc[i][0]; pk.y = acc[i][1]; pk.z = acc[i][2]; pk.w = acc[i][3];
    *reinterpret_cast<float4*>(Og + idx) = pk;
  }
}

// ---------------------------------------------------------------------------
extern "C" void kernel_launch(void* const* d_in, const int* in_sizes, int n_in,
                              void* d_out, int out_size, void* d_ws, size_t ws_size,
                              hipStream_t stream) {
  (void)in_sizes; (void)n_in; (void)out_size; (void)ws_size;
  const float* x    = (const float*)d_in[0];
  const float* Wq   = (const float*)d_in[1];
  const float* Wk   = (const float*)d_in[2];
  const float* Wv   = (const float*)d_in[3];
  const float* Wo   = (const float*)d_in[4];
  const float* cosb = (const float*)d_in[5];
  const float* sinb = (const float*)d_in[6];

  u16* ws = (u16*)d_ws;
  u16* Q = ws;                            // [B][H][T][D] bf16
  u16* K = Q + (size_t)M_ * C_;
  u16* V = K + (size_t)M_ * C_;
  u16* Y = V + (size_t)M_ * C_;           // [B*T][C] bf16
  float* out = (float*)d_out;

  dim3 g1(M_ / 64, C_ / 64, 3);
  qkv_gemm<<<g1, 256, 0, stream>>>(x, Wq, Wk, Wv, Q, K, V);

  rope_rms<<<dim3(2 * B_ * H_ * T_ / 4), 256, 0, stream>>>(Q, K, cosb, sinb);

  attn<<<dim3(T_ / 32, B_ * H_), 256, 0, stream>>>(Q, K, V, Y);

  out_gemm<<<dim3(M_ / 64, C_ / 64), 256, 0, stream>>>(Y, Wo, out);
}

// Round 5
// 518.573 us; speedup vs baseline: 3.7657x; 3.7657x over previous
//
#include <hip/hip_runtime.h>
#include <hip/hip_bf16.h>
#include <stdint.h>

#define B_ 8
#define T_ 2048
#define C_ 384
#define H_ 6
#define D_ 64
#define M_ (B_*T_)   // 16384

typedef unsigned short u16;
typedef __attribute__((ext_vector_type(8))) short short8;
typedef __attribute__((ext_vector_type(4))) float floatx4;

__device__ __forceinline__ float b2f(u16 v) {
  union { unsigned u; float f; } x; x.u = ((unsigned)v) << 16; return x.f;
}
__device__ __forceinline__ u16 f2b(float f) {
  union { float f; unsigned u; } x; x.f = f;
  unsigned r = x.u + 0x7fffu + ((x.u >> 16) & 1u);  // round-nearest-even
  return (u16)(r >> 16);
}

// ---------------------------------------------------------------------------
// Kernel 1: fused QKV projection (fp32 inputs).  q[m,n] = sum_k x[m,k]*W[n,k]
// grid = (M/64, 384/64, 3); z picks Wq/Wk/Wv.
// z=0/1 (Q,K): scatter to [B][H][T][D] bf16.
// z=2  (V)  : scatter TRANSPOSED to Vt[B][H][D][T] bf16 (free transpose for
//             the MFMA attention's V^T operand).
// ---------------------------------------------------------------------------
__global__ __launch_bounds__(256) void qkv_gemm(
    const float* __restrict__ Xg,
    const float* __restrict__ Wqg, const float* __restrict__ Wkg, const float* __restrict__ Wvg,
    u16* __restrict__ Qo, u16* __restrict__ Ko, u16* __restrict__ Vto)
{
  const int z = blockIdx.z;
  const float* Wg = (z == 0) ? Wqg : (z == 1 ? Wkg : Wvg);
  const int m0 = blockIdx.x * 64;
  const int n0 = blockIdx.y * 64;

  __shared__ float As[32][68];  // [k][m]
  __shared__ float Bs[32][68];  // [k][n]

  const int tid = threadIdx.x;
  const int lr = tid >> 2;          // 0..63 staging row
  const int lc = (tid & 3) * 8;     // 0,8,16,24 staging col
  const int tr = tid >> 4;          // 0..15 -> rows tr*4..+3
  const int tc = tid & 15;          // 0..15 -> cols tc*4..+3

  float acc[4][4] = {};

  for (int k0 = 0; k0 < 384; k0 += 32) {
    float4 xa = *reinterpret_cast<const float4*>(Xg + (size_t)(m0 + lr) * C_ + k0 + lc);
    float4 xb = *reinterpret_cast<const float4*>(Xg + (size_t)(m0 + lr) * C_ + k0 + lc + 4);
    float4 wa = *reinterpret_cast<const float4*>(Wg + (size_t)(n0 + lr) * C_ + k0 + lc);
    float4 wb = *reinterpret_cast<const float4*>(Wg + (size_t)(n0 + lr) * C_ + k0 + lc + 4);
    __syncthreads();
    As[lc + 0][lr] = xa.x; As[lc + 1][lr] = xa.y; As[lc + 2][lr] = xa.z; As[lc + 3][lr] = xa.w;
    As[lc + 4][lr] = xb.x; As[lc + 5][lr] = xb.y; As[lc + 6][lr] = xb.z; As[lc + 7][lr] = xb.w;
    Bs[lc + 0][lr] = wa.x; Bs[lc + 1][lr] = wa.y; Bs[lc + 2][lr] = wa.z; Bs[lc + 3][lr] = wa.w;
    Bs[lc + 4][lr] = wb.x; Bs[lc + 5][lr] = wb.y; Bs[lc + 6][lr] = wb.z; Bs[lc + 7][lr] = wb.w;
    __syncthreads();
#pragma unroll
    for (int kk = 0; kk < 32; kk++) {
      float4 a = *reinterpret_cast<const float4*>(&As[kk][tr * 4]);
      float4 b = *reinterpret_cast<const float4*>(&Bs[kk][tc * 4]);
      acc[0][0] += a.x * b.x; acc[0][1] += a.x * b.y; acc[0][2] += a.x * b.z; acc[0][3] += a.x * b.w;
      acc[1][0] += a.y * b.x; acc[1][1] += a.y * b.y; acc[1][2] += a.y * b.z; acc[1][3] += a.y * b.w;
      acc[2][0] += a.z * b.x; acc[2][1] += a.z * b.y; acc[2][2] += a.z * b.z; acc[2][3] += a.z * b.w;
      acc[3][0] += a.w * b.x; acc[3][1] += a.w * b.y; acc[3][2] += a.w * b.z; acc[3][3] += a.w * b.w;
    }
  }

  const int hh = n0 >> 6;            // head (n0 is a multiple of 64)
  const int bb = m0 >> 11;           // batch (2048 rows per batch, block never straddles)
  if (z == 2) {
    // Vt[((b*H+h)*D + d)*T + t], d = tc*4+j, t = m0%T + tr*4 + i (i packs ushort4)
    const int t0 = (m0 & (T_ - 1)) + tr * 4;
    const size_t vb = ((size_t)(bb * H_ + hh)) * D_ * T_;
#pragma unroll
    for (int j = 0; j < 4; j++) {
      ushort4 pk;
      pk.x = f2b(acc[0][j]); pk.y = f2b(acc[1][j]); pk.z = f2b(acc[2][j]); pk.w = f2b(acc[3][j]);
      *reinterpret_cast<ushort4*>(Vto + vb + (size_t)(tc * 4 + j) * T_ + t0) = pk;
    }
  } else {
    u16* Og = (z == 0) ? Qo : Ko;
#pragma unroll
    for (int i = 0; i < 4; i++) {
      int m = m0 + tr * 4 + i;
      int t = m & (T_ - 1);
      size_t idx = (((size_t)(bb * H_ + hh)) * T_ + t) * D_ + tc * 4;
      ushort4 pk;
      pk.x = f2b(acc[i][0]); pk.y = f2b(acc[i][1]); pk.z = f2b(acc[i][2]); pk.w = f2b(acc[i][3]);
      *reinterpret_cast<ushort4*>(Og + idx) = pk;
    }
  }
}

// ---------------------------------------------------------------------------
// Kernel 2: RoPE + RMSNorm in-place on Q and K ([B][H][T][D] bf16 rows).
// One wave per row; 4 rows per 256-thread block. V untouched.
// ---------------------------------------------------------------------------
__global__ __launch_bounds__(256) void rope_rms(
    u16* __restrict__ Q, u16* __restrict__ K,
    const float* __restrict__ cosb, const float* __restrict__ sinb)
{
  const int R = B_ * H_ * T_;
  int row = blockIdx.x * 4 + (threadIdx.x >> 6);
  int lane = threadIdx.x & 63;
  u16* base = (row < R) ? Q : K;
  int r = (row < R) ? row : row - R;
  int t = r & (T_ - 1);
  u16* p = base + (size_t)r * D_;

  float v = b2f(p[lane]);
  int ci = t * 32 + (lane & 31);
  float c = cosb[ci], s = sinb[ci];
  float partner = __shfl_xor(v, 32, 64);
  float y = (lane < 32) ? (v * c + partner * s) : (v * c - partner * s);

  float ss = y * y;
#pragma unroll
  for (int off = 1; off < 64; off <<= 1) ss += __shfl_xor(ss, off, 64);
  float scale = rsqrtf(ss * (1.0f / 64.0f) + 1e-5f);
  p[lane] = f2b(y * scale);
}

// ---------------------------------------------------------------------------
// Kernel 3: MFMA flash attention per (b,h). 64 q-rows/block (16 per wave),
// key tiles of 64.  S^T = K·Q^T (C-layout cols = q -> per-lane scalar m,l),
// O^T = V^T·P^T with P^T B-fragments built via register shuffles.
// LDS tiles row-major with 16B-chunk XOR swizzle (conflict-free b128 reads).
// ---------------------------------------------------------------------------
__global__ __launch_bounds__(256) void attn_mfma(
    const u16* __restrict__ Qg, const u16* __restrict__ Kg,
    const u16* __restrict__ Vtg, u16* __restrict__ Yg)
{
  __shared__ __align__(16) u16 smem[12288];   // Qs[0,4096) Ks[4096,8192) Vs[8192,12288)
  u16* Qs = smem;
  u16* Ks = smem + 4096;
  u16* Vs = smem + 8192;

  const int tid = threadIdx.x;
  const int w = tid >> 6;
  const int lane = tid & 63;
  const int quad = lane >> 4;      // 0..3
  const int c = lane & 15;

  const int bh = blockIdx.y;
  const int q0 = blockIdx.x * 64;
  const size_t baseQK = (size_t)bh * T_ * D_;
  const size_t baseV  = (size_t)bh * D_ * T_;

  // stage Q tile 64x64 (rows q0..q0+63), chunk-swizzled
  {
    int r = tid >> 2, ch = tid & 3;
    const u16* s = Qg + baseQK + (size_t)(q0 + r) * D_ + ch * 8;
    uint4 a = *reinterpret_cast<const uint4*>(s);
    uint4 b = *reinterpret_cast<const uint4*>(s + 32);
    *reinterpret_cast<uint4*>(Qs + r * 64 + ((ch ^ (r & 7)) * 8)) = a;
    *reinterpret_cast<uint4*>(Qs + r * 64 + (((ch + 4) ^ (r & 7)) * 8)) = b;
  }

  floatx4 o_acc[4];
#pragma unroll
  for (int i = 0; i < 4; i++) o_acc[i] = (floatx4){0.f, 0.f, 0.f, 0.f};
  float m_run = -1e30f, l_run = 0.0f;

  const int qrow = w * 16 + c;

  for (int kt = 0; kt < T_; kt += 64) {
    __syncthreads();
    {
      int r = tid >> 2, ch = tid & 3;
      const u16* s = Kg + baseQK + (size_t)(kt + r) * D_ + ch * 8;
      uint4 a = *reinterpret_cast<const uint4*>(s);
      uint4 b = *reinterpret_cast<const uint4*>(s + 32);
      *reinterpret_cast<uint4*>(Ks + r * 64 + ((ch ^ (r & 7)) * 8)) = a;
      *reinterpret_cast<uint4*>(Ks + r * 64 + (((ch + 4) ^ (r & 7)) * 8)) = b;
      const u16* sv = Vtg + baseV + (size_t)r * T_ + kt + ch * 8;   // row r = d
      uint4 va = *reinterpret_cast<const uint4*>(sv);
      uint4 vb = *reinterpret_cast<const uint4*>(sv + 32);
      *reinterpret_cast<uint4*>(Vs + r * 64 + ((ch ^ (r & 7)) * 8)) = va;
      *reinterpret_cast<uint4*>(Vs + r * 64 + (((ch + 4) ^ (r & 7)) * 8)) = vb;
    }
    __syncthreads();

    // S^T = K · Q^T  (4 key m-tiles x 16 q, K-dim = 64d in 2 steps)
    floatx4 st[4];
#pragma unroll
    for (int i = 0; i < 4; i++) st[i] = (floatx4){0.f, 0.f, 0.f, 0.f};
#pragma unroll
    for (int s2 = 0; s2 < 2; s2++) {
      short8 qf = *reinterpret_cast<const short8*>(
          Qs + qrow * 64 + (((4 * s2 + quad) ^ (qrow & 7)) * 8));
#pragma unroll
      for (int mt = 0; mt < 4; mt++) {
        int krow = mt * 16 + c;
        short8 kf = *reinterpret_cast<const short8*>(
            Ks + krow * 64 + (((4 * s2 + quad) ^ (krow & 7)) * 8));
        st[mt] = __builtin_amdgcn_mfma_f32_16x16x32_bf16(kf, qf, st[mt], 0, 0, 0);
      }
    }

    // online softmax over this lane's q-column (1/sqrt(64)=0.125 fused via fmaf)
    float mx = st[0][0];
#pragma unroll
    for (int mt = 0; mt < 4; mt++)
#pragma unroll
      for (int r = 0; r < 4; r++) mx = fmaxf(mx, st[mt][r]);
    mx = fmaxf(mx, __shfl_xor(mx, 16, 64));
    mx = fmaxf(mx, __shfl_xor(mx, 32, 64));
    float m_new = fmaxf(m_run, 0.125f * mx);
    float alpha = __expf(m_run - m_new);
    float p[4][4];
    float ls = 0.0f;
#pragma unroll
    for (int mt = 0; mt < 4; mt++)
#pragma unroll
      for (int r = 0; r < 4; r++) {
        float pv = __expf(fmaf(st[mt][r], 0.125f, -m_new));
        p[mt][r] = pv;
        ls += pv;
      }
    ls += __shfl_xor(ls, 16, 64);
    ls += __shfl_xor(ls, 32, 64);
    l_run = l_run * alpha + ls;
    m_run = m_new;
#pragma unroll
    for (int mt = 0; mt < 4; mt++) {
      o_acc[mt][0] *= alpha; o_acc[mt][1] *= alpha;
      o_acc[mt][2] *= alpha; o_acc[mt][3] *= alpha;
    }

    // O^T += V^T · P^T.  B-frag of P^T via shuffles:
    // b[j] = P^T[32*s2 + quad*8 + j][c] = p[2*s2+(quad>>1)][j&3] from lane
    //        (((quad&1)*2 + (j>>2))<<4) | c
    const int slA = (((quad & 1) * 2) << 4) | c;
    const int slB = slA + 16;
    const bool hiTile = (quad >> 1) != 0;
#pragma unroll
    for (int s2 = 0; s2 < 2; s2++) {
      float va[4], vb[4];
#pragma unroll
      for (int r = 0; r < 4; r++) {
        float x0 = __shfl(p[2 * s2][r], slA, 64);
        float x1 = __shfl(p[2 * s2 + 1][r], slA, 64);
        va[r] = hiTile ? x1 : x0;
        float y0 = __shfl(p[2 * s2][r], slB, 64);
        float y1 = __shfl(p[2 * s2 + 1][r], slB, 64);
        vb[r] = hiTile ? y1 : y0;
      }
      short8 bf;
#pragma unroll
      for (int r = 0; r < 4; r++) {
        bf[r] = (short)f2b(va[r]);
        bf[r + 4] = (short)f2b(vb[r]);
      }
#pragma unroll
      for (int mt = 0; mt < 4; mt++) {
        int vrow = mt * 16 + c;
        short8 vf = *reinterpret_cast<const short8*>(
            Vs + vrow * 64 + (((4 * s2 + quad) ^ (vrow & 7)) * 8));
        o_acc[mt] = __builtin_amdgcn_mfma_f32_16x16x32_bf16(vf, bf, o_acc[mt], 0, 0, 0);
      }
    }
  }

  // epilogue: O^T (d-major regs) -> LDS transpose -> coalesced Y[b][t][h][d]
  __syncthreads();                       // retire last K/V reads (Ot aliases Ks/Vs)
  u16* Ot = smem + 4096 + w * 1152;      // per-wave 16q x 72d (pad), 2304 B
  float inv = 1.0f / l_run;
#pragma unroll
  for (int mt = 0; mt < 4; mt++) {
    ushort4 pk;
    pk.x = f2b(o_acc[mt][0] * inv);
    pk.y = f2b(o_acc[mt][1] * inv);
    pk.z = f2b(o_acc[mt][2] * inv);
    pk.w = f2b(o_acc[mt][3] * inv);
    *reinterpret_cast<ushort4*>(Ot + c * 72 + mt * 16 + quad * 4) = pk;
  }
  __syncthreads();                       // order cross-lane LDS writes before reads
  {
    int rq = lane >> 2, dc = (lane & 3) * 16;
    uint4 r0 = *reinterpret_cast<const uint4*>(Ot + rq * 72 + dc);
    uint4 r1 = *reinterpret_cast<const uint4*>(Ot + rq * 72 + dc + 8);
    int t = q0 + w * 16 + rq;
    int b = bh / H_, h = bh % H_;
    size_t yi = ((size_t)b * T_ + t) * C_ + h * 64 + dc;
    *reinterpret_cast<uint4*>(Yg + yi) = r0;
    *reinterpret_cast<uint4*>(Yg + yi + 8) = r1;
  }
}

// ---------------------------------------------------------------------------
// Kernel 4: out = Y @ Wo^T.  Y bf16 (ws), Wo fp32 (input), out fp32 (d_out).
// ---------------------------------------------------------------------------
__global__ __launch_bounds__(256) void out_gemm(
    const u16* __restrict__ Xg, const float* __restrict__ Wg, float* __restrict__ Og)
{
  const int m0 = blockIdx.x * 64;
  const int n0 = blockIdx.y * 64;

  __shared__ float As[32][68];
  __shared__ float Bs[32][68];

  const int tid = threadIdx.x;
  const int lr = tid >> 2;
  const int lc = (tid & 3) * 8;
  const int tr = tid >> 4;
  const int tc = tid & 15;

  float acc[4][4] = {};

  for (int k0 = 0; k0 < 384; k0 += 32) {
    uint4 xa = *reinterpret_cast<const uint4*>(Xg + (size_t)(m0 + lr) * C_ + k0 + lc);
    float4 wa = *reinterpret_cast<const float4*>(Wg + (size_t)(n0 + lr) * C_ + k0 + lc);
    float4 wb = *reinterpret_cast<const float4*>(Wg + (size_t)(n0 + lr) * C_ + k0 + lc + 4);
    __syncthreads();
    const u16* xs = reinterpret_cast<const u16*>(&xa);
#pragma unroll
    for (int i = 0; i < 8; i++) As[lc + i][lr] = b2f(xs[i]);
    Bs[lc + 0][lr] = wa.x; Bs[lc + 1][lr] = wa.y; Bs[lc + 2][lr] = wa.z; Bs[lc + 3][lr] = wa.w;
    Bs[lc + 4][lr] = wb.x; Bs[lc + 5][lr] = wb.y; Bs[lc + 6][lr] = wb.z; Bs[lc + 7][lr] = wb.w;
    __syncthreads();
#pragma unroll
    for (int kk = 0; kk < 32; kk++) {
      float4 a = *reinterpret_cast<const float4*>(&As[kk][tr * 4]);
      float4 b = *reinterpret_cast<const float4*>(&Bs[kk][tc * 4]);
      acc[0][0] += a.x * b.x; acc[0][1] += a.x * b.y; acc[0][2] += a.x * b.z; acc[0][3] += a.x * b.w;
      acc[1][0] += a.y * b.x; acc[1][1] += a.y * b.y; acc[1][2] += a.y * b.z; acc[1][3] += a.y * b.w;
      acc[2][0] += a.z * b.x; acc[2][1] += a.z * b.y; acc[2][2] += a.z * b.z; acc[2][3] += a.z * b.w;
      acc[3][0] += a.w * b.x; acc[3][1] += a.w * b.y; acc[3][2] += a.w * b.z; acc[3][3] += a.w * b.w;
    }
  }

#pragma unroll
  for (int i = 0; i < 4; i++) {
    int mrow = m0 + tr * 4 + i;
    size_t idx = (size_t)mrow * C_ + n0 + tc * 4;
    float4 pk;
    pk.x = acc[i][0]; pk.y = acc[i][1]; pk.z = acc[i][2]; pk.w = acc[i][3];
    *reinterpret_cast<float4*>(Og + idx) = pk;
  }
}

// ---------------------------------------------------------------------------
extern "C" void kernel_launch(void* const* d_in, const int* in_sizes, int n_in,
                              void* d_out, int out_size, void* d_ws, size_t ws_size,
                              hipStream_t stream) {
  (void)in_sizes; (void)n_in; (void)out_size; (void)ws_size;
  const float* x    = (const float*)d_in[0];
  const float* Wq   = (const float*)d_in[1];
  const float* Wk   = (const float*)d_in[2];
  const float* Wv   = (const float*)d_in[3];
  const float* Wo   = (const float*)d_in[4];
  const float* cosb = (const float*)d_in[5];
  const float* sinb = (const float*)d_in[6];

  const size_t MC = (size_t)M_ * C_;
  u16* ws = (u16*)d_ws;
  u16* Q  = ws;                  // [B][H][T][D] bf16
  u16* K  = Q + MC;              // [B][H][T][D] bf16
  u16* Vt = K + MC;              // [B][H][D][T] bf16 (transposed V)
  u16* Y  = Vt + MC;             // [B*T][C] bf16
  float* out = (float*)d_out;

  dim3 g1(M_ / 64, C_ / 64, 3);
  qkv_gemm<<<g1, 256, 0, stream>>>(x, Wq, Wk, Wv, Q, K, Vt);

  rope_rms<<<dim3(2 * B_ * H_ * T_ / 4), 256, 0, stream>>>(Q, K, cosb, sinb);

  attn_mfma<<<dim3(T_ / 64, B_ * H_), 256, 0, stream>>>(Q, K, Vt, Y);

  out_gemm<<<dim3(M_ / 64, C_ / 64), 256, 0, stream>>>(Y, Wo, out);
}

// Round 6
// 348.246 us; speedup vs baseline: 5.6076x; 1.4891x over previous
//
#include <hip/hip_runtime.h>
#include <hip/hip_bf16.h>
#include <stdint.h>

#define B_ 8
#define T_ 2048
#define C_ 384
#define H_ 6
#define D_ 64
#define M_ (B_*T_)   // 16384

typedef unsigned short u16;
typedef __attribute__((ext_vector_type(8))) short short8;
typedef __attribute__((ext_vector_type(4))) float floatx4;

__device__ __forceinline__ float b2f(u16 v) {
  union { unsigned u; float f; } x; x.u = ((unsigned)v) << 16; return x.f;
}
__device__ __forceinline__ u16 f2b(float f) {
  union { float f; unsigned u; } x; x.f = f;
  unsigned r = x.u + 0x7fffu + ((x.u >> 16) & 1u);  // round-nearest-even
  return (u16)(r >> 16);
}

// ---------------------------------------------------------------------------
// Kernel 0: fp32 -> bf16 conversion (vectorized, n multiple of 4)
// ---------------------------------------------------------------------------
__global__ __launch_bounds__(256) void cvt_bf16(
    const float* __restrict__ src, u16* __restrict__ dst, int n4)
{
  int i = blockIdx.x * 256 + threadIdx.x;
  if (i < n4) {
    float4 v = reinterpret_cast<const float4*>(src)[i];
    ushort4 p;
    p.x = f2b(v.x); p.y = f2b(v.y); p.z = f2b(v.z); p.w = f2b(v.w);
    reinterpret_cast<ushort4*>(dst)[i] = p;
  }
}

// ---------------------------------------------------------------------------
// Kernel 1: MFMA QKV projection, bf16 in, fused RoPE+RMSNorm epilogue (z<2).
// C[m,n] = sum_k X[m,k] W[n,k].  grid=(M/128, 384/64, 3), 256 thr (4 waves).
// BM=128 BN=64(one head) BK=64.  Wave w: m in [w*32,+32), full n.
// z=0/1: epilogue LDS round-trip -> RoPE (rotation => RMS scale from x) ->
//        Q/K [B][H][T][D] bf16 coalesced.   z=2: register scatter to
//        Vt [B][H][D][T] bf16.
// ---------------------------------------------------------------------------
__global__ __launch_bounds__(256) void qkv_mfma(
    const u16* __restrict__ Xb,
    const u16* __restrict__ Wqb, const u16* __restrict__ Wkb, const u16* __restrict__ Wvb,
    const float* __restrict__ cosb, const float* __restrict__ sinb,
    u16* __restrict__ Qo, u16* __restrict__ Ko, u16* __restrict__ Vto)
{
  __shared__ __align__(16) u16 smem[128 * 64 + 64 * 64];  // As | Bs (24.5 KB)
  u16* As = smem;
  u16* Bs = smem + 128 * 64;

  const int z = blockIdx.z;
  const u16* Wb = (z == 0) ? Wqb : (z == 1 ? Wkb : Wvb);
  const int m0 = blockIdx.x * 128;
  const int hh = blockIdx.y;
  const int n0 = hh * 64;

  const int tid = threadIdx.x;
  const int w = tid >> 6;
  const int lane = tid & 63;
  const int quad = lane >> 4;
  const int c = lane & 15;

  floatx4 acc[2][4];
#pragma unroll
  for (int i = 0; i < 2; i++)
#pragma unroll
    for (int j = 0; j < 4; j++) acc[i][j] = (floatx4){0.f, 0.f, 0.f, 0.f};

  const int ra = tid >> 1, ca = (tid & 1) * 4;     // A staging: row, base chunk
  const int rb = tid >> 2, cb = (tid & 3) * 2;     // B staging

  for (int k0 = 0; k0 < 384; k0 += 64) {
    uint4 a[4];
#pragma unroll
    for (int j = 0; j < 4; j++)
      a[j] = *reinterpret_cast<const uint4*>(Xb + (size_t)(m0 + ra) * C_ + k0 + (ca + j) * 8);
    uint4 b0 = *reinterpret_cast<const uint4*>(Wb + (size_t)(n0 + rb) * C_ + k0 + cb * 8);
    uint4 b1 = *reinterpret_cast<const uint4*>(Wb + (size_t)(n0 + rb) * C_ + k0 + (cb + 1) * 8);
    __syncthreads();
#pragma unroll
    for (int j = 0; j < 4; j++)
      *reinterpret_cast<uint4*>(As + ra * 64 + (((ca + j) ^ (ra & 7)) * 8)) = a[j];
    *reinterpret_cast<uint4*>(Bs + rb * 64 + ((cb ^ (rb & 7)) * 8)) = b0;
    *reinterpret_cast<uint4*>(Bs + rb * 64 + (((cb + 1) ^ (rb & 7)) * 8)) = b1;
    __syncthreads();

#pragma unroll
    for (int ks = 0; ks < 2; ks++) {
      short8 af[2], bf[4];
#pragma unroll
      for (int mi = 0; mi < 2; mi++) {
        int row = w * 32 + mi * 16 + c;
        af[mi] = *reinterpret_cast<const short8*>(
            As + row * 64 + (((ks * 4 + quad) ^ (row & 7)) * 8));
      }
#pragma unroll
      for (int ni = 0; ni < 4; ni++) {
        int row = ni * 16 + c;
        bf[ni] = *reinterpret_cast<const short8*>(
            Bs + row * 64 + (((ks * 4 + quad) ^ (row & 7)) * 8));
      }
#pragma unroll
      for (int mi = 0; mi < 2; mi++)
#pragma unroll
        for (int ni = 0; ni < 4; ni++)
          acc[mi][ni] = __builtin_amdgcn_mfma_f32_16x16x32_bf16(af[mi], bf[ni], acc[mi][ni], 0, 0, 0);
    }
  }

  const int bb = m0 >> 11;
  const int tbase = m0 & (T_ - 1);

  if (z == 2) {
    // Vt[((b*H+h)*D + d)*T + t]; d = ni*16+c, t = tbase + w*32+mi*16+quad*4 (+r packed)
    const size_t vb = ((size_t)(bb * H_ + hh)) * D_ * T_;
#pragma unroll
    for (int mi = 0; mi < 2; mi++) {
      int t = tbase + w * 32 + mi * 16 + quad * 4;
#pragma unroll
      for (int ni = 0; ni < 4; ni++) {
        int d = ni * 16 + c;
        ushort4 pk;
        pk.x = f2b(acc[mi][ni][0]); pk.y = f2b(acc[mi][ni][1]);
        pk.z = f2b(acc[mi][ni][2]); pk.w = f2b(acc[mi][ni][3]);
        *reinterpret_cast<ushort4*>(Vto + vb + (size_t)d * T_ + t) = pk;
      }
    }
  } else {
    // Epilogue LDS: Ep[row][72] u16 (pad 72 => conflict-free row reads)
    __syncthreads();
    u16* Ep = smem;
#pragma unroll
    for (int mi = 0; mi < 2; mi++)
#pragma unroll
      for (int ni = 0; ni < 4; ni++) {
        int row = w * 32 + mi * 16 + quad * 4;
        int col = ni * 16 + c;
#pragma unroll
        for (int r = 0; r < 4; r++)
          Ep[(row + r) * 72 + col] = f2b(acc[mi][ni][r]);
      }
    __syncthreads();

    // RoPE + RMS: 2 threads per row (half = 32 d each)
    const int rr = tid >> 1, half = tid & 1;
    const int t = tbase + rr;
    const u16* rowp = Ep + rr * 72;
    float x[64];
#pragma unroll
    for (int j = 0; j < 8; j++) {
      uint4 v = *reinterpret_cast<const uint4*>(rowp + j * 8);
      const u16* e = reinterpret_cast<const u16*>(&v);
#pragma unroll
      for (int i = 0; i < 8; i++) x[j * 8 + i] = b2f(e[i]);
    }
    float ss = 0.0f;
#pragma unroll
    for (int i = 0; i < 64; i++) ss += x[i] * x[i];
    float scale = rsqrtf(ss * (1.0f / 64.0f) + 1e-5f);

    u16* Og = (z == 0) ? Qo : Ko;
    u16* dst = Og + (((size_t)(bb * H_ + hh)) * T_ + t) * D_ + half * 32;
    const float* cp = cosb + t * 32;
    const float* sp = sinb + t * 32;
#pragma unroll
    for (int j = 0; j < 8; j++) {
      float4 cv = *reinterpret_cast<const float4*>(cp + j * 4);
      float4 sv = *reinterpret_cast<const float4*>(sp + j * 4);
      float cs[4] = {cv.x, cv.y, cv.z, cv.w};
      float sn[4] = {sv.x, sv.y, sv.z, sv.w};
      ushort4 pk;
      u16* pke = reinterpret_cast<u16*>(&pk);
#pragma unroll
      for (int i = 0; i < 4; i++) {
        int idx = j * 4 + i;  // 0..31
        float y = (half == 0) ? (x[idx] * cs[i] + x[idx + 32] * sn[i])
                              : (x[idx + 32] * cs[i] - x[idx] * sn[i]);
        pke[i] = f2b(y * scale);
      }
      *reinterpret_cast<ushort4*>(dst + j * 4) = pk;
    }
  }
}

// ---------------------------------------------------------------------------
// Kernel 3: MFMA flash attention per (b,h). 64 q-rows/block (16 per wave),
// key tiles of 64.  S^T = K·Q^T;  O^T = V^T·P^T (P^T B-frags via shuffles).
// ---------------------------------------------------------------------------
__global__ __launch_bounds__(256) void attn_mfma(
    const u16* __restrict__ Qg, const u16* __restrict__ Kg,
    const u16* __restrict__ Vtg, u16* __restrict__ Yg)
{
  __shared__ __align__(16) u16 smem[12288];   // Qs | Ks | Vs
  u16* Qs = smem;
  u16* Ks = smem + 4096;
  u16* Vs = smem + 8192;

  const int tid = threadIdx.x;
  const int w = tid >> 6;
  const int lane = tid & 63;
  const int quad = lane >> 4;
  const int c = lane & 15;

  const int bh = blockIdx.y;
  const int q0 = blockIdx.x * 64;
  const size_t baseQK = (size_t)bh * T_ * D_;
  const size_t baseV  = (size_t)bh * D_ * T_;

  {
    int r = tid >> 2, ch = tid & 3;
    const u16* s = Qg + baseQK + (size_t)(q0 + r) * D_ + ch * 8;
    uint4 a = *reinterpret_cast<const uint4*>(s);
    uint4 b = *reinterpret_cast<const uint4*>(s + 32);
    *reinterpret_cast<uint4*>(Qs + r * 64 + ((ch ^ (r & 7)) * 8)) = a;
    *reinterpret_cast<uint4*>(Qs + r * 64 + (((ch + 4) ^ (r & 7)) * 8)) = b;
  }

  floatx4 o_acc[4];
#pragma unroll
  for (int i = 0; i < 4; i++) o_acc[i] = (floatx4){0.f, 0.f, 0.f, 0.f};
  float m_run = -1e30f, l_run = 0.0f;

  const int qrow = w * 16 + c;

  for (int kt = 0; kt < T_; kt += 64) {
    __syncthreads();
    {
      int r = tid >> 2, ch = tid & 3;
      const u16* s = Kg + baseQK + (size_t)(kt + r) * D_ + ch * 8;
      uint4 a = *reinterpret_cast<const uint4*>(s);
      uint4 b = *reinterpret_cast<const uint4*>(s + 32);
      *reinterpret_cast<uint4*>(Ks + r * 64 + ((ch ^ (r & 7)) * 8)) = a;
      *reinterpret_cast<uint4*>(Ks + r * 64 + (((ch + 4) ^ (r & 7)) * 8)) = b;
      const u16* sv = Vtg + baseV + (size_t)r * T_ + kt + ch * 8;
      uint4 va = *reinterpret_cast<const uint4*>(sv);
      uint4 vb = *reinterpret_cast<const uint4*>(sv + 32);
      *reinterpret_cast<uint4*>(Vs + r * 64 + ((ch ^ (r & 7)) * 8)) = va;
      *reinterpret_cast<uint4*>(Vs + r * 64 + (((ch + 4) ^ (r & 7)) * 8)) = vb;
    }
    __syncthreads();

    floatx4 st[4];
#pragma unroll
    for (int i = 0; i < 4; i++) st[i] = (floatx4){0.f, 0.f, 0.f, 0.f};
#pragma unroll
    for (int s2 = 0; s2 < 2; s2++) {
      short8 qf = *reinterpret_cast<const short8*>(
          Qs + qrow * 64 + (((4 * s2 + quad) ^ (qrow & 7)) * 8));
#pragma unroll
      for (int mt = 0; mt < 4; mt++) {
        int krow = mt * 16 + c;
        short8 kf = *reinterpret_cast<const short8*>(
            Ks + krow * 64 + (((4 * s2 + quad) ^ (krow & 7)) * 8));
        st[mt] = __builtin_amdgcn_mfma_f32_16x16x32_bf16(kf, qf, st[mt], 0, 0, 0);
      }
    }

    float mx = st[0][0];
#pragma unroll
    for (int mt = 0; mt < 4; mt++)
#pragma unroll
      for (int r = 0; r < 4; r++) mx = fmaxf(mx, st[mt][r]);
    mx = fmaxf(mx, __shfl_xor(mx, 16, 64));
    mx = fmaxf(mx, __shfl_xor(mx, 32, 64));
    float m_new = fmaxf(m_run, 0.125f * mx);
    float alpha = __expf(m_run - m_new);
    float p[4][4];
    float ls = 0.0f;
#pragma unroll
    for (int mt = 0; mt < 4; mt++)
#pragma unroll
      for (int r = 0; r < 4; r++) {
        float pv = __expf(fmaf(st[mt][r], 0.125f, -m_new));
        p[mt][r] = pv;
        ls += pv;
      }
    ls += __shfl_xor(ls, 16, 64);
    ls += __shfl_xor(ls, 32, 64);
    l_run = l_run * alpha + ls;
    m_run = m_new;
#pragma unroll
    for (int mt = 0; mt < 4; mt++) {
      o_acc[mt][0] *= alpha; o_acc[mt][1] *= alpha;
      o_acc[mt][2] *= alpha; o_acc[mt][3] *= alpha;
    }

    const int slA = (((quad & 1) * 2) << 4) | c;
    const int slB = slA + 16;
    const bool hiTile = (quad >> 1) != 0;
#pragma unroll
    for (int s2 = 0; s2 < 2; s2++) {
      float va[4], vb[4];
#pragma unroll
      for (int r = 0; r < 4; r++) {
        float x0 = __shfl(p[2 * s2][r], slA, 64);
        float x1 = __shfl(p[2 * s2 + 1][r], slA, 64);
        va[r] = hiTile ? x1 : x0;
        float y0 = __shfl(p[2 * s2][r], slB, 64);
        float y1 = __shfl(p[2 * s2 + 1][r], slB, 64);
        vb[r] = hiTile ? y1 : y0;
      }
      short8 bf;
#pragma unroll
      for (int r = 0; r < 4; r++) {
        bf[r] = (short)f2b(va[r]);
        bf[r + 4] = (short)f2b(vb[r]);
      }
#pragma unroll
      for (int mt = 0; mt < 4; mt++) {
        int vrow = mt * 16 + c;
        short8 vf = *reinterpret_cast<const short8*>(
            Vs + vrow * 64 + (((4 * s2 + quad) ^ (vrow & 7)) * 8));
        o_acc[mt] = __builtin_amdgcn_mfma_f32_16x16x32_bf16(vf, bf, o_acc[mt], 0, 0, 0);
      }
    }
  }

  __syncthreads();
  u16* Ot = smem + 4096 + w * 1152;
  float inv = 1.0f / l_run;
#pragma unroll
  for (int mt = 0; mt < 4; mt++) {
    ushort4 pk;
    pk.x = f2b(o_acc[mt][0] * inv);
    pk.y = f2b(o_acc[mt][1] * inv);
    pk.z = f2b(o_acc[mt][2] * inv);
    pk.w = f2b(o_acc[mt][3] * inv);
    *reinterpret_cast<ushort4*>(Ot + c * 72 + mt * 16 + quad * 4) = pk;
  }
  __syncthreads();
  {
    int rq = lane >> 2, dc = (lane & 3) * 16;
    uint4 r0 = *reinterpret_cast<const uint4*>(Ot + rq * 72 + dc);
    uint4 r1 = *reinterpret_cast<const uint4*>(Ot + rq * 72 + dc + 8);
    int t = q0 + w * 16 + rq;
    int b = bh / H_, h = bh % H_;
    size_t yi = ((size_t)b * T_ + t) * C_ + h * 64 + dc;
    *reinterpret_cast<uint4*>(Yg + yi) = r0;
    *reinterpret_cast<uint4*>(Yg + yi + 8) = r1;
  }
}

// ---------------------------------------------------------------------------
// Kernel 4: MFMA out projection.  out[m,n] = sum_k Y[m,k] Wo[n,k], fp32 out.
// Same core as qkv_mfma; scalar fp32 epilogue stores (64B runs).
// ---------------------------------------------------------------------------
__global__ __launch_bounds__(256) void out_mfma(
    const u16* __restrict__ Xb, const u16* __restrict__ Wb, float* __restrict__ Og)
{
  __shared__ __align__(16) u16 smem[128 * 64 + 64 * 64];
  u16* As = smem;
  u16* Bs = smem + 128 * 64;

  const int m0 = blockIdx.x * 128;
  const int n0 = blockIdx.y * 64;

  const int tid = threadIdx.x;
  const int w = tid >> 6;
  const int lane = tid & 63;
  const int quad = lane >> 4;
  const int c = lane & 15;

  floatx4 acc[2][4];
#pragma unroll
  for (int i = 0; i < 2; i++)
#pragma unroll
    for (int j = 0; j < 4; j++) acc[i][j] = (floatx4){0.f, 0.f, 0.f, 0.f};

  const int ra = tid >> 1, ca = (tid & 1) * 4;
  const int rb = tid >> 2, cb = (tid & 3) * 2;

  for (int k0 = 0; k0 < 384; k0 += 64) {
    uint4 a[4];
#pragma unroll
    for (int j = 0; j < 4; j++)
      a[j] = *reinterpret_cast<const uint4*>(Xb + (size_t)(m0 + ra) * C_ + k0 + (ca + j) * 8);
    uint4 b0 = *reinterpret_cast<const uint4*>(Wb + (size_t)(n0 + rb) * C_ + k0 + cb * 8);
    uint4 b1 = *reinterpret_cast<const uint4*>(Wb + (size_t)(n0 + rb) * C_ + k0 + (cb + 1) * 8);
    __syncthreads();
#pragma unroll
    for (int j = 0; j < 4; j++)
      *reinterpret_cast<uint4*>(As + ra * 64 + (((ca + j) ^ (ra & 7)) * 8)) = a[j];
    *reinterpret_cast<uint4*>(Bs + rb * 64 + ((cb ^ (rb & 7)) * 8)) = b0;
    *reinterpret_cast<uint4*>(Bs + rb * 64 + (((cb + 1) ^ (rb & 7)) * 8)) = b1;
    __syncthreads();

#pragma unroll
    for (int ks = 0; ks < 2; ks++) {
      short8 af[2], bf[4];
#pragma unroll
      for (int mi = 0; mi < 2; mi++) {
        int row = w * 32 + mi * 16 + c;
        af[mi] = *reinterpret_cast<const short8*>(
            As + row * 64 + (((ks * 4 + quad) ^ (row & 7)) * 8));
      }
#pragma unroll
      for (int ni = 0; ni < 4; ni++) {
        int row = ni * 16 + c;
        bf[ni] = *reinterpret_cast<const short8*>(
            Bs + row * 64 + (((ks * 4 + quad) ^ (row & 7)) * 8));
      }
#pragma unroll
      for (int mi = 0; mi < 2; mi++)
#pragma unroll
        for (int ni = 0; ni < 4; ni++)
          acc[mi][ni] = __builtin_amdgcn_mfma_f32_16x16x32_bf16(af[mi], bf[ni], acc[mi][ni], 0, 0, 0);
    }
  }

#pragma unroll
  for (int mi = 0; mi < 2; mi++)
#pragma unroll
    for (int ni = 0; ni < 4; ni++) {
      int mrow = m0 + w * 32 + mi * 16 + quad * 4;
      int n = n0 + ni * 16 + c;
#pragma unroll
      for (int r = 0; r < 4; r++)
        Og[(size_t)(mrow + r) * C_ + n] = acc[mi][ni][r];
    }
}

// ---------------------------------------------------------------------------
extern "C" void kernel_launch(void* const* d_in, const int* in_sizes, int n_in,
                              void* d_out, int out_size, void* d_ws, size_t ws_size,
                              hipStream_t stream) {
  (void)in_sizes; (void)n_in; (void)out_size; (void)ws_size;
  const float* x    = (const float*)d_in[0];
  const float* Wq   = (const float*)d_in[1];
  const float* Wk   = (const float*)d_in[2];
  const float* Wv   = (const float*)d_in[3];
  const float* Wo   = (const float*)d_in[4];
  const float* cosb = (const float*)d_in[5];
  const float* sinb = (const float*)d_in[6];

  const size_t MC = (size_t)M_ * C_;    // 6291456
  const size_t WN = (size_t)C_ * C_;    // 147456
  u16* ws = (u16*)d_ws;
  u16* xb  = ws;                        // bf16 [M][C]
  u16* Wqb = xb + MC;
  u16* Wkb = Wqb + WN;
  u16* Wvb = Wkb + WN;
  u16* Wob = Wvb + WN;
  u16* Q   = Wob + WN;                  // [B][H][T][D]
  u16* K   = Q + MC;
  u16* Vt  = K + MC;                    // [B][H][D][T]
  u16* Y   = Vt + MC;                   // [B*T][C]
  float* out = (float*)d_out;

  cvt_bf16<<<dim3((int)(MC / 4 / 256)), 256, 0, stream>>>(x, xb, (int)(MC / 4));
  cvt_bf16<<<dim3((int)(WN / 4 / 256)), 256, 0, stream>>>(Wq, Wqb, (int)(WN / 4));
  cvt_bf16<<<dim3((int)(WN / 4 / 256)), 256, 0, stream>>>(Wk, Wkb, (int)(WN / 4));
  cvt_bf16<<<dim3((int)(WN / 4 / 256)), 256, 0, stream>>>(Wv, Wvb, (int)(WN / 4));
  cvt_bf16<<<dim3((int)(WN / 4 / 256)), 256, 0, stream>>>(Wo, Wob, (int)(WN / 4));

  qkv_mfma<<<dim3(M_ / 128, H_, 3), 256, 0, stream>>>(
      xb, Wqb, Wkb, Wvb, cosb, sinb, Q, K, Vt);

  attn_mfma<<<dim3(T_ / 64, B_ * H_), 256, 0, stream>>>(Q, K, Vt, Y);

  out_mfma<<<dim3(M_ / 128, H_), 256, 0, stream>>>(Y, Wob, out);
}

// Round 7
// 306.234 us; speedup vs baseline: 6.3769x; 1.1372x over previous
//
#include <hip/hip_runtime.h>
#include <hip/hip_bf16.h>
#include <stdint.h>

#define B_ 8
#define T_ 2048
#define C_ 384
#define H_ 6
#define D_ 64
#define M_ (B_*T_)   // 16384

typedef unsigned short u16;
typedef unsigned int u32;
typedef __attribute__((ext_vector_type(8))) short short8;
typedef __attribute__((ext_vector_type(4))) float floatx4;

__device__ __forceinline__ float b2f(u16 v) {
  union { unsigned u; float f; } x; x.u = ((unsigned)v) << 16; return x.f;
}
__device__ __forceinline__ u16 f2b(float f) {
  union { float f; unsigned u; } x; x.f = f;
  unsigned r = x.u + 0x7fffu + ((x.u >> 16) & 1u);  // round-nearest-even
  return (u16)(r >> 16);
}
// pack (a -> lo16, b -> hi16) as bf16 pair, RNE
__device__ __forceinline__ u32 pack_bf16(float a, float b) {
  union { __hip_bfloat162 h; u32 u; } x;
  x.h = __float22bfloat162_rn(float2{a, b});
  return x.u;
}

// ---------------------------------------------------------------------------
// Kernel 0: fp32 -> bf16 conversion (vectorized, n multiple of 4)
// ---------------------------------------------------------------------------
__global__ __launch_bounds__(256) void cvt_bf16(
    const float* __restrict__ src, u16* __restrict__ dst, int n4)
{
  int i = blockIdx.x * 256 + threadIdx.x;
  if (i < n4) {
    float4 v = reinterpret_cast<const float4*>(src)[i];
    ushort4 p;
    p.x = f2b(v.x); p.y = f2b(v.y); p.z = f2b(v.z); p.w = f2b(v.w);
    reinterpret_cast<ushort4*>(dst)[i] = p;
  }
}

// ---------------------------------------------------------------------------
// Kernel 1: MFMA QKV projection, bf16 in, fused RoPE+RMSNorm epilogue (z<2).
// grid=(M/128, H, 3).  z=2: register scatter to Vt [B][H][D][T].
// ---------------------------------------------------------------------------
__global__ __launch_bounds__(256) void qkv_mfma(
    const u16* __restrict__ Xb,
    const u16* __restrict__ Wqb, const u16* __restrict__ Wkb, const u16* __restrict__ Wvb,
    const float* __restrict__ cosb, const float* __restrict__ sinb,
    u16* __restrict__ Qo, u16* __restrict__ Ko, u16* __restrict__ Vto)
{
  __shared__ __align__(16) u16 smem[128 * 64 + 64 * 64];  // As | Bs (24.5 KB)
  u16* As = smem;
  u16* Bs = smem + 128 * 64;

  const int z = blockIdx.z;
  const u16* Wb = (z == 0) ? Wqb : (z == 1 ? Wkb : Wvb);
  const int m0 = blockIdx.x * 128;
  const int hh = blockIdx.y;
  const int n0 = hh * 64;

  const int tid = threadIdx.x;
  const int w = tid >> 6;
  const int lane = tid & 63;
  const int quad = lane >> 4;
  const int c = lane & 15;

  floatx4 acc[2][4];
#pragma unroll
  for (int i = 0; i < 2; i++)
#pragma unroll
    for (int j = 0; j < 4; j++) acc[i][j] = (floatx4){0.f, 0.f, 0.f, 0.f};

  const int ra = tid >> 1, ca = (tid & 1) * 4;
  const int rb = tid >> 2, cb = (tid & 3) * 2;

  for (int k0 = 0; k0 < 384; k0 += 64) {
    uint4 a[4];
#pragma unroll
    for (int j = 0; j < 4; j++)
      a[j] = *reinterpret_cast<const uint4*>(Xb + (size_t)(m0 + ra) * C_ + k0 + (ca + j) * 8);
    uint4 b0 = *reinterpret_cast<const uint4*>(Wb + (size_t)(n0 + rb) * C_ + k0 + cb * 8);
    uint4 b1 = *reinterpret_cast<const uint4*>(Wb + (size_t)(n0 + rb) * C_ + k0 + (cb + 1) * 8);
    __syncthreads();
#pragma unroll
    for (int j = 0; j < 4; j++)
      *reinterpret_cast<uint4*>(As + ra * 64 + (((ca + j) ^ (ra & 7)) * 8)) = a[j];
    *reinterpret_cast<uint4*>(Bs + rb * 64 + ((cb ^ (rb & 7)) * 8)) = b0;
    *reinterpret_cast<uint4*>(Bs + rb * 64 + (((cb + 1) ^ (rb & 7)) * 8)) = b1;
    __syncthreads();

#pragma unroll
    for (int ks = 0; ks < 2; ks++) {
      short8 af[2], bf[4];
#pragma unroll
      for (int mi = 0; mi < 2; mi++) {
        int row = w * 32 + mi * 16 + c;
        af[mi] = *reinterpret_cast<const short8*>(
            As + row * 64 + (((ks * 4 + quad) ^ (row & 7)) * 8));
      }
#pragma unroll
      for (int ni = 0; ni < 4; ni++) {
        int row = ni * 16 + c;
        bf[ni] = *reinterpret_cast<const short8*>(
            Bs + row * 64 + (((ks * 4 + quad) ^ (row & 7)) * 8));
      }
#pragma unroll
      for (int mi = 0; mi < 2; mi++)
#pragma unroll
        for (int ni = 0; ni < 4; ni++)
          acc[mi][ni] = __builtin_amdgcn_mfma_f32_16x16x32_bf16(af[mi], bf[ni], acc[mi][ni], 0, 0, 0);
    }
  }

  const int bb = m0 >> 11;
  const int tbase = m0 & (T_ - 1);

  if (z == 2) {
    const size_t vb = ((size_t)(bb * H_ + hh)) * D_ * T_;
#pragma unroll
    for (int mi = 0; mi < 2; mi++) {
      int t = tbase + w * 32 + mi * 16 + quad * 4;
#pragma unroll
      for (int ni = 0; ni < 4; ni++) {
        int d = ni * 16 + c;
        ushort4 pk;
        pk.x = f2b(acc[mi][ni][0]); pk.y = f2b(acc[mi][ni][1]);
        pk.z = f2b(acc[mi][ni][2]); pk.w = f2b(acc[mi][ni][3]);
        *reinterpret_cast<ushort4*>(Vto + vb + (size_t)d * T_ + t) = pk;
      }
    }
  } else {
    __syncthreads();
    u16* Ep = smem;
#pragma unroll
    for (int mi = 0; mi < 2; mi++)
#pragma unroll
      for (int ni = 0; ni < 4; ni++) {
        int row = w * 32 + mi * 16 + quad * 4;
        int col = ni * 16 + c;
#pragma unroll
        for (int r = 0; r < 4; r++)
          Ep[(row + r) * 72 + col] = f2b(acc[mi][ni][r]);
      }
    __syncthreads();

    const int rr = tid >> 1, half = tid & 1;
    const int t = tbase + rr;
    const u16* rowp = Ep + rr * 72;
    float x[64];
#pragma unroll
    for (int j = 0; j < 8; j++) {
      uint4 v = *reinterpret_cast<const uint4*>(rowp + j * 8);
      const u16* e = reinterpret_cast<const u16*>(&v);
#pragma unroll
      for (int i = 0; i < 8; i++) x[j * 8 + i] = b2f(e[i]);
    }
    float ss = 0.0f;
#pragma unroll
    for (int i = 0; i < 64; i++) ss += x[i] * x[i];
    float scale = rsqrtf(ss * (1.0f / 64.0f) + 1e-5f);

    u16* Og = (z == 0) ? Qo : Ko;
    u16* dst = Og + (((size_t)(bb * H_ + hh)) * T_ + t) * D_ + half * 32;
    const float* cp = cosb + t * 32;
    const float* sp = sinb + t * 32;
#pragma unroll
    for (int j = 0; j < 8; j++) {
      float4 cv = *reinterpret_cast<const float4*>(cp + j * 4);
      float4 sv = *reinterpret_cast<const float4*>(sp + j * 4);
      float cs[4] = {cv.x, cv.y, cv.z, cv.w};
      float sn[4] = {sv.x, sv.y, sv.z, sv.w};
      ushort4 pk;
      u16* pke = reinterpret_cast<u16*>(&pk);
#pragma unroll
      for (int i = 0; i < 4; i++) {
        int idx = j * 4 + i;
        float y = (half == 0) ? (x[idx] * cs[i] + x[idx + 32] * sn[i])
                              : (x[idx + 32] * cs[i] - x[idx] * sn[i]);
        pke[i] = f2b(y * scale);
      }
      *reinterpret_cast<ushort4*>(dst + j * 4) = pk;
    }
  }
}

// ---------------------------------------------------------------------------
// Kernel 3: MFMA flash attention, FIXED-MAX softmax.
// RMSNorm on q,k => |q|=|k|=8 => |score| <= 8 (Cauchy-Schwarz), so
// p = exp(s - 8) needs no running max / alpha / rescale; softmax is
// shift-invariant so the result is unchanged.
// S^T = K·Q^T;  O^T = V^T·P^T with P^T B-frags via pack-then-shuffle.
// ---------------------------------------------------------------------------
__global__ __launch_bounds__(256) void attn_mfma(
    const u16* __restrict__ Qg, const u16* __restrict__ Kg,
    const u16* __restrict__ Vtg, u16* __restrict__ Yg)
{
  __shared__ __align__(16) u16 smem[12288];   // Qs | Ks | Vs
  u16* Qs = smem;
  u16* Ks = smem + 4096;
  u16* Vs = smem + 8192;

  const int tid = threadIdx.x;
  const int w = tid >> 6;
  const int lane = tid & 63;
  const int quad = lane >> 4;
  const int c = lane & 15;

  const int bh = blockIdx.y;
  const int q0 = blockIdx.x * 64;
  const size_t baseQK = (size_t)bh * T_ * D_;
  const size_t baseV  = (size_t)bh * D_ * T_;

  {
    int r = tid >> 2, ch = tid & 3;
    const u16* s = Qg + baseQK + (size_t)(q0 + r) * D_ + ch * 8;
    uint4 a = *reinterpret_cast<const uint4*>(s);
    uint4 b = *reinterpret_cast<const uint4*>(s + 32);
    *reinterpret_cast<uint4*>(Qs + r * 64 + ((ch ^ (r & 7)) * 8)) = a;
    *reinterpret_cast<uint4*>(Qs + r * 64 + (((ch + 4) ^ (r & 7)) * 8)) = b;
  }
  __syncthreads();

  // hoist loop-invariant Q fragments (qrow fixed per lane)
  const int qrow = w * 16 + c;
  short8 qf0 = *reinterpret_cast<const short8*>(
      Qs + qrow * 64 + (((0 + quad) ^ (qrow & 7)) * 8));
  short8 qf1 = *reinterpret_cast<const short8*>(
      Qs + qrow * 64 + (((4 + quad) ^ (qrow & 7)) * 8));

  floatx4 o_acc[4];
#pragma unroll
  for (int i = 0; i < 4; i++) o_acc[i] = (floatx4){0.f, 0.f, 0.f, 0.f};
  float l_part = 0.0f;

  const int slA = (((quad & 1) * 2) << 4) | c;
  const int slB = slA + 16;
  const bool hiTile = (quad >> 1) != 0;

  for (int kt = 0; kt < T_; kt += 64) {
    __syncthreads();
    {
      int r = tid >> 2, ch = tid & 3;
      const u16* s = Kg + baseQK + (size_t)(kt + r) * D_ + ch * 8;
      uint4 a = *reinterpret_cast<const uint4*>(s);
      uint4 b = *reinterpret_cast<const uint4*>(s + 32);
      *reinterpret_cast<uint4*>(Ks + r * 64 + ((ch ^ (r & 7)) * 8)) = a;
      *reinterpret_cast<uint4*>(Ks + r * 64 + (((ch + 4) ^ (r & 7)) * 8)) = b;
      const u16* sv = Vtg + baseV + (size_t)r * T_ + kt + ch * 8;
      uint4 va = *reinterpret_cast<const uint4*>(sv);
      uint4 vb = *reinterpret_cast<const uint4*>(sv + 32);
      *reinterpret_cast<uint4*>(Vs + r * 64 + ((ch ^ (r & 7)) * 8)) = va;
      *reinterpret_cast<uint4*>(Vs + r * 64 + (((ch + 4) ^ (r & 7)) * 8)) = vb;
    }
    __syncthreads();

    // S^T = K · Q^T
    floatx4 st[4];
#pragma unroll
    for (int i = 0; i < 4; i++) st[i] = (floatx4){0.f, 0.f, 0.f, 0.f};
#pragma unroll
    for (int mt = 0; mt < 4; mt++) {
      int krow = mt * 16 + c;
      short8 kf0 = *reinterpret_cast<const short8*>(
          Ks + krow * 64 + (((0 + quad) ^ (krow & 7)) * 8));
      st[mt] = __builtin_amdgcn_mfma_f32_16x16x32_bf16(kf0, qf0, st[mt], 0, 0, 0);
      short8 kf1 = *reinterpret_cast<const short8*>(
          Ks + krow * 64 + (((4 + quad) ^ (krow & 7)) * 8));
      st[mt] = __builtin_amdgcn_mfma_f32_16x16x32_bf16(kf1, qf1, st[mt], 0, 0, 0);
    }

    // fixed-max softmax: p = exp(0.125*s - 8), accumulate per-lane l
    float p[4][4];
#pragma unroll
    for (int mt = 0; mt < 4; mt++)
#pragma unroll
      for (int r = 0; r < 4; r++) {
        float pv = __expf(fmaf(st[mt][r], 0.125f, -8.0f));
        p[mt][r] = pv;
        l_part += pv;
      }

    // O^T += V^T · P^T.  Pack (tile 2s2 -> lo, 2s2+1 -> hi), shuffle once,
    // merge halves by hiTile.
#pragma unroll
    for (int s2 = 0; s2 < 2; s2++) {
      u32 pk[4];
#pragma unroll
      for (int r = 0; r < 4; r++)
        pk[r] = pack_bf16(p[2 * s2][r], p[2 * s2 + 1][r]);
      u32 wa[4], wb[4];
#pragma unroll
      for (int r = 0; r < 4; r++) {
        wa[r] = (u32)__shfl((int)pk[r], slA, 64);
        wb[r] = (u32)__shfl((int)pk[r], slB, 64);
      }
      u32 bfr[4];
      if (hiTile) {
        bfr[0] = (wa[0] >> 16) | (wa[1] & 0xffff0000u);
        bfr[1] = (wa[2] >> 16) | (wa[3] & 0xffff0000u);
        bfr[2] = (wb[0] >> 16) | (wb[1] & 0xffff0000u);
        bfr[3] = (wb[2] >> 16) | (wb[3] & 0xffff0000u);
      } else {
        bfr[0] = (wa[0] & 0xffffu) | (wa[1] << 16);
        bfr[1] = (wa[2] & 0xffffu) | (wa[3] << 16);
        bfr[2] = (wb[0] & 0xffffu) | (wb[1] << 16);
        bfr[3] = (wb[2] & 0xffffu) | (wb[3] << 16);
      }
      short8 bf;
      u32* bfu = reinterpret_cast<u32*>(&bf);
      bfu[0] = bfr[0]; bfu[1] = bfr[1]; bfu[2] = bfr[2]; bfu[3] = bfr[3];
#pragma unroll
      for (int mt = 0; mt < 4; mt++) {
        int vrow = mt * 16 + c;
        short8 vf = *reinterpret_cast<const short8*>(
            Vs + vrow * 64 + (((4 * s2 + quad) ^ (vrow & 7)) * 8));
        o_acc[mt] = __builtin_amdgcn_mfma_f32_16x16x32_bf16(vf, bf, o_acc[mt], 0, 0, 0);
      }
    }
  }

  // total l for this lane's q-column: sum the 4 quads
  float l_run = l_part;
  l_run += __shfl_xor(l_run, 16, 64);
  l_run += __shfl_xor(l_run, 32, 64);

  __syncthreads();
  u16* Ot = smem + 4096 + w * 1152;
  float inv = 1.0f / l_run;
#pragma unroll
  for (int mt = 0; mt < 4; mt++) {
    ushort4 pk;
    pk.x = f2b(o_acc[mt][0] * inv);
    pk.y = f2b(o_acc[mt][1] * inv);
    pk.z = f2b(o_acc[mt][2] * inv);
    pk.w = f2b(o_acc[mt][3] * inv);
    *reinterpret_cast<ushort4*>(Ot + c * 72 + mt * 16 + quad * 4) = pk;
  }
  __syncthreads();
  {
    int rq = lane >> 2, dc = (lane & 3) * 16;
    uint4 r0 = *reinterpret_cast<const uint4*>(Ot + rq * 72 + dc);
    uint4 r1 = *reinterpret_cast<const uint4*>(Ot + rq * 72 + dc + 8);
    int t = q0 + w * 16 + rq;
    int b = bh / H_, h = bh % H_;
    size_t yi = ((size_t)b * T_ + t) * C_ + h * 64 + dc;
    *reinterpret_cast<uint4*>(Yg + yi) = r0;
    *reinterpret_cast<uint4*>(Yg + yi + 8) = r1;
  }
}

// ---------------------------------------------------------------------------
// Kernel 4: MFMA out projection.  out[m,n] = sum_k Y[m,k] Wo[n,k], fp32 out.
// ---------------------------------------------------------------------------
__global__ __launch_bounds__(256) void out_mfma(
    const u16* __restrict__ Xb, const u16* __restrict__ Wb, float* __restrict__ Og)
{
  __shared__ __align__(16) u16 smem[128 * 64 + 64 * 64];
  u16* As = smem;
  u16* Bs = smem + 128 * 64;

  const int m0 = blockIdx.x * 128;
  const int n0 = blockIdx.y * 64;

  const int tid = threadIdx.x;
  const int w = tid >> 6;
  const int lane = tid & 63;
  const int quad = lane >> 4;
  const int c = lane & 15;

  floatx4 acc[2][4];
#pragma unroll
  for (int i = 0; i < 2; i++)
#pragma unroll
    for (int j = 0; j < 4; j++) acc[i][j] = (floatx4){0.f, 0.f, 0.f, 0.f};

  const int ra = tid >> 1, ca = (tid & 1) * 4;
  const int rb = tid >> 2, cb = (tid & 3) * 2;

  for (int k0 = 0; k0 < 384; k0 += 64) {
    uint4 a[4];
#pragma unroll
    for (int j = 0; j < 4; j++)
      a[j] = *reinterpret_cast<const uint4*>(Xb + (size_t)(m0 + ra) * C_ + k0 + (ca + j) * 8);
    uint4 b0 = *reinterpret_cast<const uint4*>(Wb + (size_t)(n0 + rb) * C_ + k0 + cb * 8);
    uint4 b1 = *reinterpret_cast<const uint4*>(Wb + (size_t)(n0 + rb) * C_ + k0 + (cb + 1) * 8);
    __syncthreads();
#pragma unroll
    for (int j = 0; j < 4; j++)
      *reinterpret_cast<uint4*>(As + ra * 64 + (((ca + j) ^ (ra & 7)) * 8)) = a[j];
    *reinterpret_cast<uint4*>(Bs + rb * 64 + ((cb ^ (rb & 7)) * 8)) = b0;
    *reinterpret_cast<uint4*>(Bs + rb * 64 + (((cb + 1) ^ (rb & 7)) * 8)) = b1;
    __syncthreads();

#pragma unroll
    for (int ks = 0; ks < 2; ks++) {
      short8 af[2], bf[4];
#pragma unroll
      for (int mi = 0; mi < 2; mi++) {
        int row = w * 32 + mi * 16 + c;
        af[mi] = *reinterpret_cast<const short8*>(
            As + row * 64 + (((ks * 4 + quad) ^ (row & 7)) * 8));
      }
#pragma unroll
      for (int ni = 0; ni < 4; ni++) {
        int row = ni * 16 + c;
        bf[ni] = *reinterpret_cast<const short8*>(
            Bs + row * 64 + (((ks * 4 + quad) ^ (row & 7)) * 8));
      }
#pragma unroll
      for (int mi = 0; mi < 2; mi++)
#pragma unroll
        for (int ni = 0; ni < 4; ni++)
          acc[mi][ni] = __builtin_amdgcn_mfma_f32_16x16x32_bf16(af[mi], bf[ni], acc[mi][ni], 0, 0, 0);
    }
  }

#pragma unroll
  for (int mi = 0; mi < 2; mi++)
#pragma unroll
    for (int ni = 0; ni < 4; ni++) {
      int mrow = m0 + w * 32 + mi * 16 + quad * 4;
      int n = n0 + ni * 16 + c;
#pragma unroll
      for (int r = 0; r < 4; r++)
        Og[(size_t)(mrow + r) * C_ + n] = acc[mi][ni][r];
    }
}

// ---------------------------------------------------------------------------
extern "C" void kernel_launch(void* const* d_in, const int* in_sizes, int n_in,
                              void* d_out, int out_size, void* d_ws, size_t ws_size,
                              hipStream_t stream) {
  (void)in_sizes; (void)n_in; (void)out_size; (void)ws_size;
  const float* x    = (const float*)d_in[0];
  const float* Wq   = (const float*)d_in[1];
  const float* Wk   = (const float*)d_in[2];
  const float* Wv   = (const float*)d_in[3];
  const float* Wo   = (const float*)d_in[4];
  const float* cosb = (const float*)d_in[5];
  const float* sinb = (const float*)d_in[6];

  const size_t MC = (size_t)M_ * C_;    // 6291456
  const size_t WN = (size_t)C_ * C_;    // 147456
  u16* ws = (u16*)d_ws;
  u16* xb  = ws;                        // bf16 [M][C]
  u16* Wqb = xb + MC;
  u16* Wkb = Wqb + WN;
  u16* Wvb = Wkb + WN;
  u16* Wob = Wvb + WN;
  u16* Q   = Wob + WN;                  // [B][H][T][D]
  u16* K   = Q + MC;
  u16* Vt  = K + MC;                    // [B][H][D][T]
  u16* Y   = Vt + MC;                   // [B*T][C]
  float* out = (float*)d_out;

  cvt_bf16<<<dim3((int)(MC / 4 / 256)), 256, 0, stream>>>(x, xb, (int)(MC / 4));
  cvt_bf16<<<dim3((int)(WN / 4 / 256)), 256, 0, stream>>>(Wq, Wqb, (int)(WN / 4));
  cvt_bf16<<<dim3((int)(WN / 4 / 256)), 256, 0, stream>>>(Wk, Wkb, (int)(WN / 4));
  cvt_bf16<<<dim3((int)(WN / 4 / 256)), 256, 0, stream>>>(Wv, Wvb, (int)(WN / 4));
  cvt_bf16<<<dim3((int)(WN / 4 / 256)), 256, 0, stream>>>(Wo, Wob, (int)(WN / 4));

  qkv_mfma<<<dim3(M_ / 128, H_, 3), 256, 0, stream>>>(
      xb, Wqb, Wkb, Wvb, cosb, sinb, Q, K, Vt);

  attn_mfma<<<dim3(T_ / 64, B_ * H_), 256, 0, stream>>>(Q, K, Vt, Y);

  out_mfma<<<dim3(M_ / 128, H_), 256, 0, stream>>>(Y, Wob, out);
}

// Round 8
// 298.047 us; speedup vs baseline: 6.5521x; 1.0275x over previous
//
#include <hip/hip_runtime.h>
#include <hip/hip_bf16.h>
#include <stdint.h>

#define B_ 8
#define T_ 2048
#define C_ 384
#define H_ 6
#define D_ 64
#define M_ (B_*T_)   // 16384

typedef unsigned short u16;
typedef unsigned int u32;
typedef __attribute__((ext_vector_type(8))) short short8;
typedef __attribute__((ext_vector_type(4))) float floatx4;

__device__ __forceinline__ float b2f(u16 v) {
  union { unsigned u; float f; } x; x.u = ((unsigned)v) << 16; return x.f;
}
__device__ __forceinline__ u16 f2b(float f) {
  union { float f; unsigned u; } x; x.f = f;
  unsigned r = x.u + 0x7fffu + ((x.u >> 16) & 1u);  // round-nearest-even
  return (u16)(r >> 16);
}
__device__ __forceinline__ u32 pack_bf16(float a, float b) {
  union { __hip_bfloat162 h; u32 u; } x;
  x.h = __float22bfloat162_rn(float2{a, b});
  return x.u;
}

// ---------------------------------------------------------------------------
// fp32 -> bf16 converts: one for x, one batched for the 4 weights
// ---------------------------------------------------------------------------
__global__ __launch_bounds__(256) void cvt_bf16(
    const float* __restrict__ src, u16* __restrict__ dst, int n4)
{
  int i = blockIdx.x * 256 + threadIdx.x;
  if (i < n4) {
    float4 v = reinterpret_cast<const float4*>(src)[i];
    ushort4 p;
    p.x = f2b(v.x); p.y = f2b(v.y); p.z = f2b(v.z); p.w = f2b(v.w);
    reinterpret_cast<ushort4*>(dst)[i] = p;
  }
}

__global__ __launch_bounds__(256) void cvt_w4(
    const float* __restrict__ s0, const float* __restrict__ s1,
    const float* __restrict__ s2, const float* __restrict__ s3,
    u16* __restrict__ d0, u16* __restrict__ d1,
    u16* __restrict__ d2, u16* __restrict__ d3, int n4)
{
  int zz = blockIdx.y;
  const float* src = (zz == 0) ? s0 : (zz == 1) ? s1 : (zz == 2) ? s2 : s3;
  u16* dst = (zz == 0) ? d0 : (zz == 1) ? d1 : (zz == 2) ? d2 : d3;
  int i = blockIdx.x * 256 + threadIdx.x;
  if (i < n4) {
    float4 v = reinterpret_cast<const float4*>(src)[i];
    ushort4 p;
    p.x = f2b(v.x); p.y = f2b(v.y); p.z = f2b(v.z); p.w = f2b(v.w);
    reinterpret_cast<ushort4*>(dst)[i] = p;
  }
}

// ---------------------------------------------------------------------------
// Fused QKV projection: X tile staged ONCE for all of Q,K,V.
// grid=(M/128, H).  BM=128, BN=64 (one head) x 3 outputs, BK=64.
// Epilogue: lane-parallel RMS (c-group shuffle reduce) + in-lane RoPE
// (pair d,d+32 = ni,ni+2 in same lane), LDS transpose only for the final
// coalesced store.  V: register scatter to Vt[B][H][D][T].
// ---------------------------------------------------------------------------
__global__ __launch_bounds__(256) void qkv_fused(
    const u16* __restrict__ Xb,
    const u16* __restrict__ Wqb, const u16* __restrict__ Wkb, const u16* __restrict__ Wvb,
    const float* __restrict__ cosb, const float* __restrict__ sinb,
    u16* __restrict__ Qo, u16* __restrict__ Ko, u16* __restrict__ Vto)
{
  __shared__ __align__(16) u16 smem[128 * 64 + 3 * 64 * 64];  // As | Bs[3] (40 KB)
  u16* As = smem;
  u16* Bs0 = smem + 128 * 64;

  const int m0 = blockIdx.x * 128;
  const int hh = blockIdx.y;
  const int n0 = hh * 64;

  const int tid = threadIdx.x;
  const int w = tid >> 6;
  const int lane = tid & 63;
  const int quad = lane >> 4;
  const int c = lane & 15;

  const u16* Wz[3] = {Wqb, Wkb, Wvb};

  floatx4 acc[3][2][4];
#pragma unroll
  for (int z = 0; z < 3; z++)
#pragma unroll
    for (int i = 0; i < 2; i++)
#pragma unroll
      for (int j = 0; j < 4; j++) acc[z][i][j] = (floatx4){0.f, 0.f, 0.f, 0.f};

  const int ra = tid >> 1, ca = (tid & 1) * 4;   // A staging: 2 thr/row
  const int rb = tid >> 2, cb = (tid & 3) * 2;   // B staging: 4 thr/row

  for (int k0 = 0; k0 < 384; k0 += 64) {
    uint4 a[4], bw[3][2];
#pragma unroll
    for (int j = 0; j < 4; j++)
      a[j] = *reinterpret_cast<const uint4*>(Xb + (size_t)(m0 + ra) * C_ + k0 + (ca + j) * 8);
#pragma unroll
    for (int z = 0; z < 3; z++) {
      bw[z][0] = *reinterpret_cast<const uint4*>(Wz[z] + (size_t)(n0 + rb) * C_ + k0 + cb * 8);
      bw[z][1] = *reinterpret_cast<const uint4*>(Wz[z] + (size_t)(n0 + rb) * C_ + k0 + (cb + 1) * 8);
    }
    __syncthreads();
#pragma unroll
    for (int j = 0; j < 4; j++)
      *reinterpret_cast<uint4*>(As + ra * 64 + (((ca + j) ^ (ra & 7)) * 8)) = a[j];
#pragma unroll
    for (int z = 0; z < 3; z++) {
      *reinterpret_cast<uint4*>(Bs0 + z * 4096 + rb * 64 + ((cb ^ (rb & 7)) * 8)) = bw[z][0];
      *reinterpret_cast<uint4*>(Bs0 + z * 4096 + rb * 64 + (((cb + 1) ^ (rb & 7)) * 8)) = bw[z][1];
    }
    __syncthreads();

#pragma unroll
    for (int ks = 0; ks < 2; ks++) {
      short8 af[2];
#pragma unroll
      for (int mi = 0; mi < 2; mi++) {
        int row = w * 32 + mi * 16 + c;
        af[mi] = *reinterpret_cast<const short8*>(
            As + row * 64 + (((ks * 4 + quad) ^ (row & 7)) * 8));
      }
#pragma unroll
      for (int z = 0; z < 3; z++) {
#pragma unroll
        for (int ni = 0; ni < 4; ni++) {
          int row = ni * 16 + c;
          short8 bf = *reinterpret_cast<const short8*>(
              Bs0 + z * 4096 + row * 64 + (((ks * 4 + quad) ^ (row & 7)) * 8));
#pragma unroll
          for (int mi = 0; mi < 2; mi++)
            acc[z][mi][ni] = __builtin_amdgcn_mfma_f32_16x16x32_bf16(af[mi], bf, acc[z][mi][ni], 0, 0, 0);
        }
      }
    }
  }

  const int bb2 = m0 >> 11;             // batch
  const int tbase = m0 & (T_ - 1);

  // ---- V: register scatter to Vt[B][H][D][T] ----
  {
    const size_t vbase = ((size_t)(bb2 * H_ + hh)) * D_ * T_;
#pragma unroll
    for (int mi = 0; mi < 2; mi++) {
      int t = tbase + w * 32 + mi * 16 + quad * 4;
#pragma unroll
      for (int ni = 0; ni < 4; ni++) {
        int d = ni * 16 + c;
        ushort4 pk;
        pk.x = f2b(acc[2][mi][ni][0]); pk.y = f2b(acc[2][mi][ni][1]);
        pk.z = f2b(acc[2][mi][ni][2]); pk.w = f2b(acc[2][mi][ni][3]);
        *reinterpret_cast<ushort4*>(Vto + vbase + (size_t)d * T_ + t) = pk;
      }
    }
  }

  // ---- Q then K: lane-parallel RMS + RoPE, LDS transpose store ----
  u16* Ep = smem;                        // 128 x 72 u16 (18 KB), aliases As/Bs
#pragma unroll
  for (int zz = 0; zz < 2; zz++) {
    __syncthreads();                     // prior LDS reads (GEMM / zz-1 copyout) done
#pragma unroll
    for (int mi = 0; mi < 2; mi++) {
      float ssr[4];
#pragma unroll
      for (int r = 0; r < 4; r++) {
        float s0 = acc[zz][mi][0][r], s1 = acc[zz][mi][1][r];
        float s2 = acc[zz][mi][2][r], s3 = acc[zz][mi][3][r];
        ssr[r] = s0 * s0 + s1 * s1 + s2 * s2 + s3 * s3;
      }
#pragma unroll
      for (int off = 1; off < 16; off <<= 1)
#pragma unroll
        for (int r = 0; r < 4; r++) ssr[r] += __shfl_xor(ssr[r], off, 64);
      int rowb = w * 32 + mi * 16 + quad * 4;
#pragma unroll
      for (int r = 0; r < 4; r++) {
        float scale = rsqrtf(ssr[r] * (1.0f / 64.0f) + 1e-5f);
        int t = tbase + rowb + r;
#pragma unroll
        for (int h2 = 0; h2 < 2; h2++) {
          float cs = cosb[t * 32 + h2 * 16 + c];
          float sn = sinb[t * 32 + h2 * 16 + c];
          float x1 = acc[zz][mi][h2][r];
          float x2 = acc[zz][mi][h2 + 2][r];
          Ep[(rowb + r) * 72 + h2 * 16 + c]       = f2b((x1 * cs + x2 * sn) * scale);
          Ep[(rowb + r) * 72 + (h2 + 2) * 16 + c] = f2b((x2 * cs - x1 * sn) * scale);
        }
      }
    }
    __syncthreads();
    {
      int row = tid >> 1, half = tid & 1;
      int t = tbase + row;
      u16* Og = (zz == 0) ? Qo : Ko;
      u16* dst = Og + (((size_t)(bb2 * H_ + hh)) * T_ + t) * D_ + half * 32;
#pragma unroll
      for (int i = 0; i < 4; i++)
        *reinterpret_cast<uint4*>(dst + i * 8) =
            *reinterpret_cast<const uint4*>(Ep + row * 72 + half * 32 + i * 8);
    }
  }
}

// ---------------------------------------------------------------------------
// MFMA flash attention, fixed-max softmax (|score|<=8 from RMSNorm +
// Cauchy-Schwarz).  Unchanged from round 7.
// ---------------------------------------------------------------------------
__global__ __launch_bounds__(256) void attn_mfma(
    const u16* __restrict__ Qg, const u16* __restrict__ Kg,
    const u16* __restrict__ Vtg, u16* __restrict__ Yg)
{
  __shared__ __align__(16) u16 smem[12288];   // Qs | Ks | Vs
  u16* Qs = smem;
  u16* Ks = smem + 4096;
  u16* Vs = smem + 8192;

  const int tid = threadIdx.x;
  const int w = tid >> 6;
  const int lane = tid & 63;
  const int quad = lane >> 4;
  const int c = lane & 15;

  const int bh = blockIdx.y;
  const int q0 = blockIdx.x * 64;
  const size_t baseQK = (size_t)bh * T_ * D_;
  const size_t baseV  = (size_t)bh * D_ * T_;

  {
    int r = tid >> 2, ch = tid & 3;
    const u16* s = Qg + baseQK + (size_t)(q0 + r) * D_ + ch * 8;
    uint4 a = *reinterpret_cast<const uint4*>(s);
    uint4 b = *reinterpret_cast<const uint4*>(s + 32);
    *reinterpret_cast<uint4*>(Qs + r * 64 + ((ch ^ (r & 7)) * 8)) = a;
    *reinterpret_cast<uint4*>(Qs + r * 64 + (((ch + 4) ^ (r & 7)) * 8)) = b;
  }
  __syncthreads();

  const int qrow = w * 16 + c;
  short8 qf0 = *reinterpret_cast<const short8*>(
      Qs + qrow * 64 + (((0 + quad) ^ (qrow & 7)) * 8));
  short8 qf1 = *reinterpret_cast<const short8*>(
      Qs + qrow * 64 + (((4 + quad) ^ (qrow & 7)) * 8));

  floatx4 o_acc[4];
#pragma unroll
  for (int i = 0; i < 4; i++) o_acc[i] = (floatx4){0.f, 0.f, 0.f, 0.f};
  float l_part = 0.0f;

  const int slA = (((quad & 1) * 2) << 4) | c;
  const int slB = slA + 16;
  const bool hiTile = (quad >> 1) != 0;

  for (int kt = 0; kt < T_; kt += 64) {
    __syncthreads();
    {
      int r = tid >> 2, ch = tid & 3;
      const u16* s = Kg + baseQK + (size_t)(kt + r) * D_ + ch * 8;
      uint4 a = *reinterpret_cast<const uint4*>(s);
      uint4 b = *reinterpret_cast<const uint4*>(s + 32);
      *reinterpret_cast<uint4*>(Ks + r * 64 + ((ch ^ (r & 7)) * 8)) = a;
      *reinterpret_cast<uint4*>(Ks + r * 64 + (((ch + 4) ^ (r & 7)) * 8)) = b;
      const u16* sv = Vtg + baseV + (size_t)r * T_ + kt + ch * 8;
      uint4 va = *reinterpret_cast<const uint4*>(sv);
      uint4 vb = *reinterpret_cast<const uint4*>(sv + 32);
      *reinterpret_cast<uint4*>(Vs + r * 64 + ((ch ^ (r & 7)) * 8)) = va;
      *reinterpret_cast<uint4*>(Vs + r * 64 + (((ch + 4) ^ (r & 7)) * 8)) = vb;
    }
    __syncthreads();

    floatx4 st[4];
#pragma unroll
    for (int i = 0; i < 4; i++) st[i] = (floatx4){0.f, 0.f, 0.f, 0.f};
#pragma unroll
    for (int mt = 0; mt < 4; mt++) {
      int krow = mt * 16 + c;
      short8 kf0 = *reinterpret_cast<const short8*>(
          Ks + krow * 64 + (((0 + quad) ^ (krow & 7)) * 8));
      st[mt] = __builtin_amdgcn_mfma_f32_16x16x32_bf16(kf0, qf0, st[mt], 0, 0, 0);
      short8 kf1 = *reinterpret_cast<const short8*>(
          Ks + krow * 64 + (((4 + quad) ^ (krow & 7)) * 8));
      st[mt] = __builtin_amdgcn_mfma_f32_16x16x32_bf16(kf1, qf1, st[mt], 0, 0, 0);
    }

    float p[4][4];
#pragma unroll
    for (int mt = 0; mt < 4; mt++)
#pragma unroll
      for (int r = 0; r < 4; r++) {
        float pv = __expf(fmaf(st[mt][r], 0.125f, -8.0f));
        p[mt][r] = pv;
        l_part += pv;
      }

#pragma unroll
    for (int s2 = 0; s2 < 2; s2++) {
      u32 pk[4];
#pragma unroll
      for (int r = 0; r < 4; r++)
        pk[r] = pack_bf16(p[2 * s2][r], p[2 * s2 + 1][r]);
      u32 wa[4], wb[4];
#pragma unroll
      for (int r = 0; r < 4; r++) {
        wa[r] = (u32)__shfl((int)pk[r], slA, 64);
        wb[r] = (u32)__shfl((int)pk[r], slB, 64);
      }
      u32 bfr[4];
      if (hiTile) {
        bfr[0] = (wa[0] >> 16) | (wa[1] & 0xffff0000u);
        bfr[1] = (wa[2] >> 16) | (wa[3] & 0xffff0000u);
        bfr[2] = (wb[0] >> 16) | (wb[1] & 0xffff0000u);
        bfr[3] = (wb[2] >> 16) | (wb[3] & 0xffff0000u);
      } else {
        bfr[0] = (wa[0] & 0xffffu) | (wa[1] << 16);
        bfr[1] = (wa[2] & 0xffffu) | (wa[3] << 16);
        bfr[2] = (wb[0] & 0xffffu) | (wb[1] << 16);
        bfr[3] = (wb[2] & 0xffffu) | (wb[3] << 16);
      }
      short8 bf;
      u32* bfu = reinterpret_cast<u32*>(&bf);
      bfu[0] = bfr[0]; bfu[1] = bfr[1]; bfu[2] = bfr[2]; bfu[3] = bfr[3];
#pragma unroll
      for (int mt = 0; mt < 4; mt++) {
        int vrow = mt * 16 + c;
        short8 vf = *reinterpret_cast<const short8*>(
            Vs + vrow * 64 + (((4 * s2 + quad) ^ (vrow & 7)) * 8));
        o_acc[mt] = __builtin_amdgcn_mfma_f32_16x16x32_bf16(vf, bf, o_acc[mt], 0, 0, 0);
      }
    }
  }

  float l_run = l_part;
  l_run += __shfl_xor(l_run, 16, 64);
  l_run += __shfl_xor(l_run, 32, 64);

  __syncthreads();
  u16* Ot = smem + 4096 + w * 1152;
  float inv = 1.0f / l_run;
#pragma unroll
  for (int mt = 0; mt < 4; mt++) {
    ushort4 pk;
    pk.x = f2b(o_acc[mt][0] * inv);
    pk.y = f2b(o_acc[mt][1] * inv);
    pk.z = f2b(o_acc[mt][2] * inv);
    pk.w = f2b(o_acc[mt][3] * inv);
    *reinterpret_cast<ushort4*>(Ot + c * 72 + mt * 16 + quad * 4) = pk;
  }
  __syncthreads();
  {
    int rq = lane >> 2, dc = (lane & 3) * 16;
    uint4 r0 = *reinterpret_cast<const uint4*>(Ot + rq * 72 + dc);
    uint4 r1 = *reinterpret_cast<const uint4*>(Ot + rq * 72 + dc + 8);
    int t = q0 + w * 16 + rq;
    int b = bh / H_, h = bh % H_;
    size_t yi = ((size_t)b * T_ + t) * C_ + h * 64 + dc;
    *reinterpret_cast<uint4*>(Yg + yi) = r0;
    *reinterpret_cast<uint4*>(Yg + yi + 8) = r1;
  }
}

// ---------------------------------------------------------------------------
// Out projection: out[m,n] = sum_k Y[m,k] Wo[n,k]; fp32 out with per-wave
// LDS-transpose epilogue for coalesced float4 stores.
// ---------------------------------------------------------------------------
__global__ __launch_bounds__(256) void out_mfma(
    const u16* __restrict__ Xb, const u16* __restrict__ Wb, float* __restrict__ Og)
{
  __shared__ __align__(16) u16 smem[17408];   // 34816 B: As|Bs, then fp32 Ep
  u16* As = smem;
  u16* Bs = smem + 128 * 64;

  const int m0 = blockIdx.x * 128;
  const int n0 = blockIdx.y * 64;

  const int tid = threadIdx.x;
  const int w = tid >> 6;
  const int lane = tid & 63;
  const int quad = lane >> 4;
  const int c = lane & 15;

  floatx4 acc[2][4];
#pragma unroll
  for (int i = 0; i < 2; i++)
#pragma unroll
    for (int j = 0; j < 4; j++) acc[i][j] = (floatx4){0.f, 0.f, 0.f, 0.f};

  const int ra = tid >> 1, ca = (tid & 1) * 4;
  const int rb = tid >> 2, cb = (tid & 3) * 2;

  for (int k0 = 0; k0 < 384; k0 += 64) {
    uint4 a[4];
#pragma unroll
    for (int j = 0; j < 4; j++)
      a[j] = *reinterpret_cast<const uint4*>(Xb + (size_t)(m0 + ra) * C_ + k0 + (ca + j) * 8);
    uint4 b0 = *reinterpret_cast<const uint4*>(Wb + (size_t)(n0 + rb) * C_ + k0 + cb * 8);
    uint4 b1 = *reinterpret_cast<const uint4*>(Wb + (size_t)(n0 + rb) * C_ + k0 + (cb + 1) * 8);
    __syncthreads();
#pragma unroll
    for (int j = 0; j < 4; j++)
      *reinterpret_cast<uint4*>(As + ra * 64 + (((ca + j) ^ (ra & 7)) * 8)) = a[j];
    *reinterpret_cast<uint4*>(Bs + rb * 64 + ((cb ^ (rb & 7)) * 8)) = b0;
    *reinterpret_cast<uint4*>(Bs + rb * 64 + (((cb + 1) ^ (rb & 7)) * 8)) = b1;
    __syncthreads();

#pragma unroll
    for (int ks = 0; ks < 2; ks++) {
      short8 af[2], bf[4];
#pragma unroll
      for (int mi = 0; mi < 2; mi++) {
        int row = w * 32 + mi * 16 + c;
        af[mi] = *reinterpret_cast<const short8*>(
            As + row * 64 + (((ks * 4 + quad) ^ (row & 7)) * 8));
      }
#pragma unroll
      for (int ni = 0; ni < 4; ni++) {
        int row = ni * 16 + c;
        bf[ni] = *reinterpret_cast<const short8*>(
            Bs + row * 64 + (((ks * 4 + quad) ^ (row & 7)) * 8));
      }
#pragma unroll
      for (int mi = 0; mi < 2; mi++)
#pragma unroll
        for (int ni = 0; ni < 4; ni++)
          acc[mi][ni] = __builtin_amdgcn_mfma_f32_16x16x32_bf16(af[mi], bf[ni], acc[mi][ni], 0, 0, 0);
    }
  }

  // per-wave fp32 transpose: Ep_w[32][68]
  __syncthreads();
  float* Ep = reinterpret_cast<float*>(smem) + w * (32 * 68);
#pragma unroll
  for (int mi = 0; mi < 2; mi++)
#pragma unroll
    for (int ni = 0; ni < 4; ni++) {
      int rw = mi * 16 + quad * 4;
      int col = ni * 16 + c;
#pragma unroll
      for (int r = 0; r < 4; r++)
        Ep[(rw + r) * 68 + col] = acc[mi][ni][r];
    }
  __syncthreads();
  {
    int rw2 = lane >> 1, half = lane & 1;
    const float* src = Ep + rw2 * 68 + half * 32;
    float* dst = Og + (size_t)(m0 + w * 32 + rw2) * C_ + n0 + half * 32;
#pragma unroll
    for (int i = 0; i < 8; i++)
      *reinterpret_cast<float4*>(dst + i * 4) =
          *reinterpret_cast<const float4*>(src + i * 4);
  }
}

// ---------------------------------------------------------------------------
extern "C" void kernel_launch(void* const* d_in, const int* in_sizes, int n_in,
                              void* d_out, int out_size, void* d_ws, size_t ws_size,
                              hipStream_t stream) {
  (void)in_sizes; (void)n_in; (void)out_size; (void)ws_size;
  const float* x    = (const float*)d_in[0];
  const float* Wq   = (const float*)d_in[1];
  const float* Wk   = (const float*)d_in[2];
  const float* Wv   = (const float*)d_in[3];
  const float* Wo   = (const float*)d_in[4];
  const float* cosb = (const float*)d_in[5];
  const float* sinb = (const float*)d_in[6];

  const size_t MC = (size_t)M_ * C_;    // 6291456
  const size_t WN = (size_t)C_ * C_;    // 147456
  u16* ws = (u16*)d_ws;
  u16* xb  = ws;                        // bf16 [M][C]
  u16* Wqb = xb + MC;
  u16* Wkb = Wqb + WN;
  u16* Wvb = Wkb + WN;
  u16* Wob = Wvb + WN;
  u16* Q   = Wob + WN;                  // [B][H][T][D]
  u16* K   = Q + MC;
  u16* Vt  = K + MC;                    // [B][H][D][T]
  u16* Y   = Vt + MC;                   // [B*T][C]
  float* out = (float*)d_out;

  cvt_bf16<<<dim3((int)(MC / 4 / 256)), 256, 0, stream>>>(x, xb, (int)(MC / 4));
  cvt_w4<<<dim3((int)(WN / 4 / 256), 4), 256, 0, stream>>>(
      Wq, Wk, Wv, Wo, Wqb, Wkb, Wvb, Wob, (int)(WN / 4));

  qkv_fused<<<dim3(M_ / 128, H_), 256, 0, stream>>>(
      xb, Wqb, Wkb, Wvb, cosb, sinb, Q, K, Vt);

  attn_mfma<<<dim3(T_ / 64, B_ * H_), 256, 0, stream>>>(Q, K, Vt, Y);

  out_mfma<<<dim3(M_ / 128, H_), 256, 0, stream>>>(Y, Wob, out);
}

// Round 9
// 292.740 us; speedup vs baseline: 6.6708x; 1.0181x over previous
//
#include <hip/hip_runtime.h>
#include <hip/hip_bf16.h>
#include <stdint.h>

#define B_ 8
#define T_ 2048
#define C_ 384
#define H_ 6
#define D_ 64
#define M_ (B_*T_)   // 16384

typedef unsigned short u16;
typedef unsigned int u32;
typedef __attribute__((ext_vector_type(8))) short short8;
typedef __attribute__((ext_vector_type(4))) float floatx4;

__device__ __forceinline__ float b2f(u16 v) {
  union { unsigned u; float f; } x; x.u = ((unsigned)v) << 16; return x.f;
}
__device__ __forceinline__ u16 f2b(float f) {
  union { float f; unsigned u; } x; x.f = f;
  unsigned r = x.u + 0x7fffu + ((x.u >> 16) & 1u);  // round-nearest-even
  return (u16)(r >> 16);
}
__device__ __forceinline__ u32 pack_bf16(float a, float b) {
  union { __hip_bfloat162 h; u32 u; } x;
  x.h = __float22bfloat162_rn(float2{a, b});
  return x.u;
}
// pack 8 fp32 (two float4) -> uint4 of bf16
__device__ __forceinline__ uint4 pack8(const float4& lo, const float4& hi) {
  uint4 r;
  r.x = pack_bf16(lo.x, lo.y); r.y = pack_bf16(lo.z, lo.w);
  r.z = pack_bf16(hi.x, hi.y); r.w = pack_bf16(hi.z, hi.w);
  return r;
}

// ---------------------------------------------------------------------------
// Fused QKV projection, fp32 inputs staged directly (in-register cvt).
// grid=(M/128, H).  BM=128, BN=64 (one head) x 3 outputs, BK=64.
// Epilogue: lane-parallel RMS + in-lane RoPE; Q/K via LDS transpose store;
// V register-scatter to Vt[B][H][D][T].
// ---------------------------------------------------------------------------
__global__ __launch_bounds__(256) void qkv_fused(
    const float* __restrict__ Xf,
    const float* __restrict__ Wqf, const float* __restrict__ Wkf, const float* __restrict__ Wvf,
    const float* __restrict__ cosb, const float* __restrict__ sinb,
    u16* __restrict__ Qo, u16* __restrict__ Ko, u16* __restrict__ Vto)
{
  __shared__ __align__(16) u16 smem[128 * 64 + 3 * 64 * 64];  // As | Bs[3] (40 KB)
  u16* As = smem;
  u16* Bs0 = smem + 128 * 64;

  const int m0 = blockIdx.x * 128;
  const int hh = blockIdx.y;
  const int n0 = hh * 64;

  const int tid = threadIdx.x;
  const int w = tid >> 6;
  const int lane = tid & 63;
  const int quad = lane >> 4;
  const int c = lane & 15;

  const float* Wz[3] = {Wqf, Wkf, Wvf};

  floatx4 acc[3][2][4];
#pragma unroll
  for (int z = 0; z < 3; z++)
#pragma unroll
    for (int i = 0; i < 2; i++)
#pragma unroll
      for (int j = 0; j < 4; j++) acc[z][i][j] = (floatx4){0.f, 0.f, 0.f, 0.f};

  const int ra = tid >> 1, ca = (tid & 1) * 4;   // A: 2 thr/row, 4 chunks each
  const int rb = tid >> 2, cb = (tid & 3) * 2;   // B: 4 thr/row, 2 chunks each

  for (int k0 = 0; k0 < 384; k0 += 64) {
    float4 af[8];
#pragma unroll
    for (int j = 0; j < 4; j++) {
      const float* p = Xf + (size_t)(m0 + ra) * C_ + k0 + (ca + j) * 8;
      af[2 * j]     = *reinterpret_cast<const float4*>(p);
      af[2 * j + 1] = *reinterpret_cast<const float4*>(p + 4);
    }
    float4 bw[3][4];
#pragma unroll
    for (int z = 0; z < 3; z++)
#pragma unroll
      for (int u = 0; u < 2; u++) {
        const float* p = Wz[z] + (size_t)(n0 + rb) * C_ + k0 + (cb + u) * 8;
        bw[z][2 * u]     = *reinterpret_cast<const float4*>(p);
        bw[z][2 * u + 1] = *reinterpret_cast<const float4*>(p + 4);
      }
    __syncthreads();
#pragma unroll
    for (int j = 0; j < 4; j++)
      *reinterpret_cast<uint4*>(As + ra * 64 + (((ca + j) ^ (ra & 7)) * 8)) =
          pack8(af[2 * j], af[2 * j + 1]);
#pragma unroll
    for (int z = 0; z < 3; z++)
#pragma unroll
      for (int u = 0; u < 2; u++)
        *reinterpret_cast<uint4*>(Bs0 + z * 4096 + rb * 64 + (((cb + u) ^ (rb & 7)) * 8)) =
            pack8(bw[z][2 * u], bw[z][2 * u + 1]);
    __syncthreads();

#pragma unroll
    for (int ks = 0; ks < 2; ks++) {
      short8 af2[2];
#pragma unroll
      for (int mi = 0; mi < 2; mi++) {
        int row = w * 32 + mi * 16 + c;
        af2[mi] = *reinterpret_cast<const short8*>(
            As + row * 64 + (((ks * 4 + quad) ^ (row & 7)) * 8));
      }
#pragma unroll
      for (int z = 0; z < 3; z++) {
#pragma unroll
        for (int ni = 0; ni < 4; ni++) {
          int row = ni * 16 + c;
          short8 bf = *reinterpret_cast<const short8*>(
              Bs0 + z * 4096 + row * 64 + (((ks * 4 + quad) ^ (row & 7)) * 8));
#pragma unroll
          for (int mi = 0; mi < 2; mi++)
            acc[z][mi][ni] = __builtin_amdgcn_mfma_f32_16x16x32_bf16(af2[mi], bf, acc[z][mi][ni], 0, 0, 0);
        }
      }
    }
  }

  const int bb2 = m0 >> 11;             // batch
  const int tbase = m0 & (T_ - 1);

  // ---- V: register scatter to Vt[B][H][D][T] ----
  {
    const size_t vbase = ((size_t)(bb2 * H_ + hh)) * D_ * T_;
#pragma unroll
    for (int mi = 0; mi < 2; mi++) {
      int t = tbase + w * 32 + mi * 16 + quad * 4;
#pragma unroll
      for (int ni = 0; ni < 4; ni++) {
        int d = ni * 16 + c;
        ushort4 pk;
        pk.x = f2b(acc[2][mi][ni][0]); pk.y = f2b(acc[2][mi][ni][1]);
        pk.z = f2b(acc[2][mi][ni][2]); pk.w = f2b(acc[2][mi][ni][3]);
        *reinterpret_cast<ushort4*>(Vto + vbase + (size_t)d * T_ + t) = pk;
      }
    }
  }

  // ---- Q then K: lane-parallel RMS + RoPE, LDS transpose store ----
  u16* Ep = smem;                        // 128 x 72 u16, aliases As/Bs
#pragma unroll
  for (int zz = 0; zz < 2; zz++) {
    __syncthreads();
#pragma unroll
    for (int mi = 0; mi < 2; mi++) {
      float ssr[4];
#pragma unroll
      for (int r = 0; r < 4; r++) {
        float s0 = acc[zz][mi][0][r], s1 = acc[zz][mi][1][r];
        float s2 = acc[zz][mi][2][r], s3 = acc[zz][mi][3][r];
        ssr[r] = s0 * s0 + s1 * s1 + s2 * s2 + s3 * s3;
      }
#pragma unroll
      for (int off = 1; off < 16; off <<= 1)
#pragma unroll
        for (int r = 0; r < 4; r++) ssr[r] += __shfl_xor(ssr[r], off, 64);
      int rowb = w * 32 + mi * 16 + quad * 4;
#pragma unroll
      for (int r = 0; r < 4; r++) {
        float scale = rsqrtf(ssr[r] * (1.0f / 64.0f) + 1e-5f);
        int t = tbase + rowb + r;
#pragma unroll
        for (int h2 = 0; h2 < 2; h2++) {
          float cs = cosb[t * 32 + h2 * 16 + c];
          float sn = sinb[t * 32 + h2 * 16 + c];
          float x1 = acc[zz][mi][h2][r];
          float x2 = acc[zz][mi][h2 + 2][r];
          Ep[(rowb + r) * 72 + h2 * 16 + c]       = f2b((x1 * cs + x2 * sn) * scale);
          Ep[(rowb + r) * 72 + (h2 + 2) * 16 + c] = f2b((x2 * cs - x1 * sn) * scale);
        }
      }
    }
    __syncthreads();
    {
      int row = tid >> 1, half = tid & 1;
      int t = tbase + row;
      u16* Og = (zz == 0) ? Qo : Ko;
      u16* dst = Og + (((size_t)(bb2 * H_ + hh)) * T_ + t) * D_ + half * 32;
#pragma unroll
      for (int i = 0; i < 4; i++)
        *reinterpret_cast<uint4*>(dst + i * 8) =
            *reinterpret_cast<const uint4*>(Ep + row * 72 + half * 32 + i * 8);
    }
  }
}

// ---------------------------------------------------------------------------
// MFMA flash attention, fixed-max softmax, 128 q-rows/block (2 subtiles/wave).
// K/V fragments read once per iter, shared across both q-subtiles.
// p = exp2(s*0.125*log2e - 8*log2e)  (one v_exp, no mul).
// ---------------------------------------------------------------------------
#define EXP2_SC 0.1803368801111244f   // 0.125 * log2(e)
#define EXP2_BI (-11.541560327111404f) // -8 * log2(e)

__global__ __launch_bounds__(256) void attn_mfma(
    const u16* __restrict__ Qg, const u16* __restrict__ Kg,
    const u16* __restrict__ Vtg, u16* __restrict__ Yg)
{
  __shared__ __align__(16) u16 smem[16384];   // Qs[0,8192) Ks[8192,12288) Vs[12288,16384)
  u16* Qs = smem;
  u16* Ks = smem + 8192;
  u16* Vs = smem + 12288;

  const int tid = threadIdx.x;
  const int w = tid >> 6;
  const int lane = tid & 63;
  const int quad = lane >> 4;
  const int c = lane & 15;

  const int bh = blockIdx.y;
  const int q0 = blockIdx.x * 128;
  const size_t baseQK = (size_t)bh * T_ * D_;
  const size_t baseV  = (size_t)bh * D_ * T_;

  // stage Q tile 128x64, chunk-swizzled (2 thr/row, 4 chunks each)
  {
    int r = tid >> 1, h4 = (tid & 1) * 4;
    const u16* s = Qg + baseQK + (size_t)(q0 + r) * D_;
#pragma unroll
    for (int j = 0; j < 4; j++) {
      uint4 v = *reinterpret_cast<const uint4*>(s + (h4 + j) * 8);
      *reinterpret_cast<uint4*>(Qs + r * 64 + (((h4 + j) ^ (r & 7)) * 8)) = v;
    }
  }
  __syncthreads();

  // hoist Q fragments for both subtiles
  short8 qf[2][2];
#pragma unroll
  for (int qs = 0; qs < 2; qs++) {
    int qr = qs * 64 + w * 16 + c;
    qf[qs][0] = *reinterpret_cast<const short8*>(
        Qs + qr * 64 + (((0 + quad) ^ (qr & 7)) * 8));
    qf[qs][1] = *reinterpret_cast<const short8*>(
        Qs + qr * 64 + (((4 + quad) ^ (qr & 7)) * 8));
  }

  floatx4 o_acc[2][4];
#pragma unroll
  for (int qs = 0; qs < 2; qs++)
#pragma unroll
    for (int i = 0; i < 4; i++) o_acc[qs][i] = (floatx4){0.f, 0.f, 0.f, 0.f};
  float l_part[2] = {0.f, 0.f};

  const int slA = (((quad & 1) * 2) << 4) | c;
  const int slB = slA + 16;
  const bool hiTile = (quad >> 1) != 0;

  for (int kt = 0; kt < T_; kt += 64) {
    __syncthreads();
    {
      int r = tid >> 2, ch = tid & 3;
      const u16* s = Kg + baseQK + (size_t)(kt + r) * D_ + ch * 8;
      uint4 a = *reinterpret_cast<const uint4*>(s);
      uint4 b = *reinterpret_cast<const uint4*>(s + 32);
      *reinterpret_cast<uint4*>(Ks + r * 64 + ((ch ^ (r & 7)) * 8)) = a;
      *reinterpret_cast<uint4*>(Ks + r * 64 + (((ch + 4) ^ (r & 7)) * 8)) = b;
      const u16* sv = Vtg + baseV + (size_t)r * T_ + kt + ch * 8;
      uint4 va = *reinterpret_cast<const uint4*>(sv);
      uint4 vb = *reinterpret_cast<const uint4*>(sv + 32);
      *reinterpret_cast<uint4*>(Vs + r * 64 + ((ch ^ (r & 7)) * 8)) = va;
      *reinterpret_cast<uint4*>(Vs + r * 64 + (((ch + 4) ^ (r & 7)) * 8)) = vb;
    }
    __syncthreads();

    // S^T = K · Q^T for both q-subtiles; K frags read once
    floatx4 st[2][4];
#pragma unroll
    for (int qs = 0; qs < 2; qs++)
#pragma unroll
      for (int i = 0; i < 4; i++) st[qs][i] = (floatx4){0.f, 0.f, 0.f, 0.f};
#pragma unroll
    for (int mt = 0; mt < 4; mt++) {
      int krow = mt * 16 + c;
      short8 kf0 = *reinterpret_cast<const short8*>(
          Ks + krow * 64 + (((0 + quad) ^ (krow & 7)) * 8));
      short8 kf1 = *reinterpret_cast<const short8*>(
          Ks + krow * 64 + (((4 + quad) ^ (krow & 7)) * 8));
#pragma unroll
      for (int qs = 0; qs < 2; qs++) {
        st[qs][mt] = __builtin_amdgcn_mfma_f32_16x16x32_bf16(kf0, qf[qs][0], st[qs][mt], 0, 0, 0);
        st[qs][mt] = __builtin_amdgcn_mfma_f32_16x16x32_bf16(kf1, qf[qs][1], st[qs][mt], 0, 0, 0);
      }
    }

    // fixed-max softmax + immediate bf16 pair packing
    u32 pk[2][2][4];
#pragma unroll
    for (int qs = 0; qs < 2; qs++) {
      float p[4][4];
#pragma unroll
      for (int mt = 0; mt < 4; mt++)
#pragma unroll
        for (int r = 0; r < 4; r++) {
          float pv = exp2f(fmaf(st[qs][mt][r], EXP2_SC, EXP2_BI));
          p[mt][r] = pv;
          l_part[qs] += pv;
        }
#pragma unroll
      for (int s2 = 0; s2 < 2; s2++)
#pragma unroll
        for (int r = 0; r < 4; r++)
          pk[qs][s2][r] = pack_bf16(p[2 * s2][r], p[2 * s2 + 1][r]);
    }

    // O^T += V^T · P^T ; V frags read once, shared across subtiles
#pragma unroll
    for (int s2 = 0; s2 < 2; s2++) {
      short8 bf[2];
#pragma unroll
      for (int qs = 0; qs < 2; qs++) {
        u32 wa[4], wb[4];
#pragma unroll
        for (int r = 0; r < 4; r++) {
          wa[r] = (u32)__shfl((int)pk[qs][s2][r], slA, 64);
          wb[r] = (u32)__shfl((int)pk[qs][s2][r], slB, 64);
        }
        u32 bfr[4];
        if (hiTile) {
          bfr[0] = (wa[0] >> 16) | (wa[1] & 0xffff0000u);
          bfr[1] = (wa[2] >> 16) | (wa[3] & 0xffff0000u);
          bfr[2] = (wb[0] >> 16) | (wb[1] & 0xffff0000u);
          bfr[3] = (wb[2] >> 16) | (wb[3] & 0xffff0000u);
        } else {
          bfr[0] = (wa[0] & 0xffffu) | (wa[1] << 16);
          bfr[1] = (wa[2] & 0xffffu) | (wa[3] << 16);
          bfr[2] = (wb[0] & 0xffffu) | (wb[1] << 16);
          bfr[3] = (wb[2] & 0xffffu) | (wb[3] << 16);
        }
        u32* bfu = reinterpret_cast<u32*>(&bf[qs]);
        bfu[0] = bfr[0]; bfu[1] = bfr[1]; bfu[2] = bfr[2]; bfu[3] = bfr[3];
      }
#pragma unroll
      for (int mt = 0; mt < 4; mt++) {
        int vrow = mt * 16 + c;
        short8 vf = *reinterpret_cast<const short8*>(
            Vs + vrow * 64 + (((4 * s2 + quad) ^ (vrow & 7)) * 8));
#pragma unroll
        for (int qs = 0; qs < 2; qs++)
          o_acc[qs][mt] = __builtin_amdgcn_mfma_f32_16x16x32_bf16(vf, bf[qs], o_acc[qs][mt], 0, 0, 0);
      }
    }
  }

  float inv[2];
#pragma unroll
  for (int qs = 0; qs < 2; qs++) {
    float l = l_part[qs];
    l += __shfl_xor(l, 16, 64);
    l += __shfl_xor(l, 32, 64);
    inv[qs] = 1.0f / l;
  }

  // epilogue: per-wave LDS transpose (2304 u16/subtile), coalesced store
  __syncthreads();
  u16* Ot = smem + w * 2304;
#pragma unroll
  for (int qs = 0; qs < 2; qs++)
#pragma unroll
    for (int mt = 0; mt < 4; mt++) {
      ushort4 pko;
      pko.x = f2b(o_acc[qs][mt][0] * inv[qs]);
      pko.y = f2b(o_acc[qs][mt][1] * inv[qs]);
      pko.z = f2b(o_acc[qs][mt][2] * inv[qs]);
      pko.w = f2b(o_acc[qs][mt][3] * inv[qs]);
      *reinterpret_cast<ushort4*>(Ot + qs * 1152 + c * 72 + mt * 16 + quad * 4) = pko;
    }
  __syncthreads();
  {
    int row = tid >> 1, half = tid & 1;     // q-row in [0,128), d-half
    int qs = row >> 6, wv = (row >> 4) & 3, rq = row & 15;
    const u16* src = smem + wv * 2304 + qs * 1152 + rq * 72 + half * 32;
    int t = q0 + row;
    int b = bh / H_, h = bh % H_;
    u16* dst = Yg + ((size_t)b * T_ + t) * C_ + h * 64 + half * 32;
#pragma unroll
    for (int i = 0; i < 4; i++)
      *reinterpret_cast<uint4*>(dst + i * 8) =
          *reinterpret_cast<const uint4*>(src + i * 8);
  }
}

// ---------------------------------------------------------------------------
// Out projection: Y bf16 (ws) x Wo fp32 (staged w/ in-register cvt) -> fp32.
// ---------------------------------------------------------------------------
__global__ __launch_bounds__(256) void out_mfma(
    const u16* __restrict__ Xb, const float* __restrict__ Wf, float* __restrict__ Og)
{
  __shared__ __align__(16) u16 smem[17408];   // As|Bs, then fp32 Ep (34816 B)
  u16* As = smem;
  u16* Bs = smem + 128 * 64;

  const int m0 = blockIdx.x * 128;
  const int n0 = blockIdx.y * 64;

  const int tid = threadIdx.x;
  const int w = tid >> 6;
  const int lane = tid & 63;
  const int quad = lane >> 4;
  const int c = lane & 15;

  floatx4 acc[2][4];
#pragma unroll
  for (int i = 0; i < 2; i++)
#pragma unroll
    for (int j = 0; j < 4; j++) acc[i][j] = (floatx4){0.f, 0.f, 0.f, 0.f};

  const int ra = tid >> 1, ca = (tid & 1) * 4;
  const int rb = tid >> 2, cb = (tid & 3) * 2;

  for (int k0 = 0; k0 < 384; k0 += 64) {
    uint4 a[4];
#pragma unroll
    for (int j = 0; j < 4; j++)
      a[j] = *reinterpret_cast<const uint4*>(Xb + (size_t)(m0 + ra) * C_ + k0 + (ca + j) * 8);
    float4 bw[4];
#pragma unroll
    for (int u = 0; u < 2; u++) {
      const float* p = Wf + (size_t)(n0 + rb) * C_ + k0 + (cb + u) * 8;
      bw[2 * u]     = *reinterpret_cast<const float4*>(p);
      bw[2 * u + 1] = *reinterpret_cast<const float4*>(p + 4);
    }
    __syncthreads();
#pragma unroll
    for (int j = 0; j < 4; j++)
      *reinterpret_cast<uint4*>(As + ra * 64 + (((ca + j) ^ (ra & 7)) * 8)) = a[j];
#pragma unroll
    for (int u = 0; u < 2; u++)
      *reinterpret_cast<uint4*>(Bs + rb * 64 + (((cb + u) ^ (rb & 7)) * 8)) =
          pack8(bw[2 * u], bw[2 * u + 1]);
    __syncthreads();

#pragma unroll
    for (int ks = 0; ks < 2; ks++) {
      short8 af[2], bf[4];
#pragma unroll
      for (int mi = 0; mi < 2; mi++) {
        int row = w * 32 + mi * 16 + c;
        af[mi] = *reinterpret_cast<const short8*>(
            As + row * 64 + (((ks * 4 + quad) ^ (row & 7)) * 8));
      }
#pragma unroll
      for (int ni = 0; ni < 4; ni++) {
        int row = ni * 16 + c;
        bf[ni] = *reinterpret_cast<const short8*>(
            Bs + row * 64 + (((ks * 4 + quad) ^ (row & 7)) * 8));
      }
#pragma unroll
      for (int mi = 0; mi < 2; mi++)
#pragma unroll
        for (int ni = 0; ni < 4; ni++)
          acc[mi][ni] = __builtin_amdgcn_mfma_f32_16x16x32_bf16(af[mi], bf[ni], acc[mi][ni], 0, 0, 0);
    }
  }

  __syncthreads();
  float* Ep = reinterpret_cast<float*>(smem) + w * (32 * 68);
#pragma unroll
  for (int mi = 0; mi < 2; mi++)
#pragma unroll
    for (int ni = 0; ni < 4; ni++) {
      int rw = mi * 16 + quad * 4;
      int col = ni * 16 + c;
#pragma unroll
      for (int r = 0; r < 4; r++)
        Ep[(rw + r) * 68 + col] = acc[mi][ni][r];
    }
  __syncthreads();
  {
    int rw2 = lane >> 1, half = lane & 1;
    const float* src = Ep + rw2 * 68 + half * 32;
    float* dst = Og + (size_t)(m0 + w * 32 + rw2) * C_ + n0 + half * 32;
#pragma unroll
    for (int i = 0; i < 8; i++)
      *reinterpret_cast<float4*>(dst + i * 4) =
          *reinterpret_cast<const float4*>(src + i * 4);
  }
}

// ---------------------------------------------------------------------------
extern "C" void kernel_launch(void* const* d_in, const int* in_sizes, int n_in,
                              void* d_out, int out_size, void* d_ws, size_t ws_size,
                              hipStream_t stream) {
  (void)in_sizes; (void)n_in; (void)out_size; (void)ws_size;
  const float* x    = (const float*)d_in[0];
  const float* Wq   = (const float*)d_in[1];
  const float* Wk   = (const float*)d_in[2];
  const float* Wv   = (const float*)d_in[3];
  const float* Wo   = (const float*)d_in[4];
  const float* cosb = (const float*)d_in[5];
  const float* sinb = (const float*)d_in[6];

  const size_t MC = (size_t)M_ * C_;    // 6291456
  u16* ws = (u16*)d_ws;
  u16* Q   = ws;                        // [B][H][T][D] bf16
  u16* K   = Q + MC;
  u16* Vt  = K + MC;                    // [B][H][D][T] bf16
  u16* Y   = Vt + MC;                   // [B*T][C] bf16
  float* out = (float*)d_out;

  qkv_fused<<<dim3(M_ / 128, H_), 256, 0, stream>>>(
      x, Wq, Wk, Wv, cosb, sinb, Q, K, Vt);

  attn_mfma<<<dim3(T_ / 128, B_ * H_), 256, 0, stream>>>(Q, K, Vt, Y);

  out_mfma<<<dim3(M_ / 128, H_), 256, 0, stream>>>(Y, Wo, out);
}